// Round 3
// baseline (1711.321 us; speedup 1.0000x reference)
//
#include <hip/hip_runtime.h>
#include <cstddef>
#include <math.h>

// ---------------- problem constants ----------------
#define B_   2
#define L_   2048
#define D_   512
#define E_   768
static const size_t LL   = (size_t)L_ * L_;     // 4194304 per batch
static const size_t SLOT = (size_t)B_ * LL;     // 8388608 per output slot

#define QK_N   ((size_t)B_ * L_ * D_)      // 2097152 elements
#define G_N    ((size_t)6 * 512 * 512)     // 1572864 elements (doubles)
#define U_N    ((size_t)6 * L_ * D_)       // 6291456 elements (floats)

// ---------------- LDS tile loaders ------------------------------------------
__device__ __forceinline__ void load_MK(const float* __restrict__ A, int lda,
                                        int m0, int k0, int tid, float S[16][64]) {
    // operand stored [M x K] row-major: transpose-store into S[k][m]
    int mi = tid >> 2;
    int kj = (tid & 3) << 2;
    const float4 v = *reinterpret_cast<const float4*>(A + (size_t)(m0 + mi) * lda + (k0 + kj));
    S[kj + 0][mi] = v.x; S[kj + 1][mi] = v.y; S[kj + 2][mi] = v.z; S[kj + 3][mi] = v.w;
}

__device__ __forceinline__ void load_KM(const float* __restrict__ A, int lda,
                                        int m0, int k0, int tid, float S[16][64]) {
    // operand stored [K x M] row-major: direct float4 into S[k][m]
    int kj = tid >> 4;
    int mi = (tid & 15) << 2;
    *reinterpret_cast<float4*>(&S[kj][mi]) =
        *reinterpret_cast<const float4*>(A + (size_t)(k0 + kj) * lda + (m0 + mi));
}

__device__ __forceinline__ void load_KM_d(const double* __restrict__ A, int lda,
                                          int m0, int k0, int tid, double S[16][64]) {
    int kj = tid >> 4;
    int mi = (tid & 15) << 2;
    const double* p = A + (size_t)(k0 + kj) * lda + (m0 + mi);
    S[kj][mi + 0] = p[0]; S[kj][mi + 1] = p[1]; S[kj][mi + 2] = p[2]; S[kj][mi + 3] = p[3];
}

// ---------------- fp64-accumulating MMA variants -----------------------------
__device__ __forceinline__ void mma16_ff(float SA[16][64], float SB[16][64],
                                         int tx, int ty, double acc[4][4]) {
#pragma unroll
    for (int kk = 0; kk < 16; ++kk) {
        float4 a = *reinterpret_cast<float4*>(&SA[kk][ty << 2]);
        float4 b = *reinterpret_cast<float4*>(&SB[kk][tx << 2]);
        double av[4] = {(double)a.x, (double)a.y, (double)a.z, (double)a.w};
        double bv[4] = {(double)b.x, (double)b.y, (double)b.z, (double)b.w};
#pragma unroll
        for (int i = 0; i < 4; ++i)
#pragma unroll
            for (int j = 0; j < 4; ++j)
                acc[i][j] = fma(av[i], bv[j], acc[i][j]);
    }
}

__device__ __forceinline__ void mma16_fd(float SA[16][64], double SB[16][64],
                                         int tx, int ty, double acc[4][4]) {
#pragma unroll
    for (int kk = 0; kk < 16; ++kk) {
        float4 a = *reinterpret_cast<float4*>(&SA[kk][ty << 2]);
        double av[4] = {(double)a.x, (double)a.y, (double)a.z, (double)a.w};
        double bv[4];
#pragma unroll
        for (int j = 0; j < 4; ++j) bv[j] = SB[kk][(tx << 2) + j];
#pragma unroll
        for (int i = 0; i < 4; ++i)
#pragma unroll
            for (int j = 0; j < 4; ++j)
                acc[i][j] = fma(av[i], bv[j], acc[i][j]);
    }
}

// ---------------- 1) projection GEMM, fp64 accumulate ------------------------
__global__ __launch_bounds__(256) void k_proj(const float* __restrict__ x,
                                              const float* __restrict__ Wq,
                                              const float* __restrict__ Wk,
                                              float* __restrict__ qbuf,
                                              float* __restrict__ kbuf) {
    __shared__ float As[16][64], Bs[16][64];
    int tid = threadIdx.x, tx = tid & 15, ty = tid >> 4;
    int n0 = blockIdx.x * 64, m0 = blockIdx.y * 64;
    const float* W = blockIdx.z ? Wk : Wq;
    float* out = blockIdx.z ? kbuf : qbuf;
    double acc[4][4] = {};
    for (int k0 = 0; k0 < E_; k0 += 16) {
        load_MK(x, E_, m0, k0, tid, As);
        load_MK(W, E_, n0, k0, tid, Bs);
        __syncthreads();
        mma16_ff(As, Bs, tx, ty, acc);
        __syncthreads();
    }
#pragma unroll
    for (int i = 0; i < 4; ++i) {
        int r = m0 + (ty << 2) + i;
#pragma unroll
        for (int j = 0; j < 4; ++j)
            out[(size_t)r * D_ + n0 + (tx << 2) + j] = (float)acc[i][j];
    }
}

// ---------------- 2) LayerNorm + RoPE, fp64 math, in place -------------------
__global__ __launch_bounds__(128) void k_lnrope(float* qbuf, float* kbuf,
                                                const float* __restrict__ qg, const float* __restrict__ qb,
                                                const float* __restrict__ kg, const float* __restrict__ kb) {
    int row = blockIdx.x;           // b*2048 + l
    int l = row & (L_ - 1);
    int tid = threadIdx.x;
    __shared__ double nrow[D_];
    __shared__ double red[4];
    for (int pass = 0; pass < 2; ++pass) {
        float* buf = pass ? kbuf : qbuf;
        const float* g  = pass ? kg : qg;
        const float* bt = pass ? kb : qb;
        float* rp = buf + (size_t)row * D_;
        float4 v = reinterpret_cast<float4*>(rp)[tid];     // tid*4
        double vv[4] = {(double)v.x, (double)v.y, (double)v.z, (double)v.w};
        double s = vv[0] + vv[1] + vv[2] + vv[3];
        double s2 = vv[0]*vv[0] + vv[1]*vv[1] + vv[2]*vv[2] + vv[3]*vv[3];
        for (int off = 32; off; off >>= 1) { s += __shfl_xor(s, off); s2 += __shfl_xor(s2, off); }
        int wv = tid >> 6;
        if ((tid & 63) == 0) { red[wv * 2] = s; red[wv * 2 + 1] = s2; }
        __syncthreads();
        double mu  = (red[0] + red[2]) * (1.0 / D_);
        double var = (red[1] + red[3]) * (1.0 / D_) - mu * mu;
        double rs = rsqrt(var + 1e-5);
        int d0 = tid * 4;
        double o[4];
#pragma unroll
        for (int c = 0; c < 4; ++c) {
            int d = d0 + c;
            o[c] = (vv[c] - mu) * rs * (double)g[d] + (double)bt[d];
        }
        __syncthreads();
#pragma unroll
        for (int c = 0; c < 4; ++c) nrow[d0 + c] = o[c];
        __syncthreads();
#pragma unroll
        for (int c = 0; c < 4; ++c) {
            int d = d0 + c;
            int idx = d & 255;
            double e = (double)idx * (1.0 / 256.0);
            double inv = pow(10000.0, -e);
            double ang = (double)l * inv;
            double s0 = sin(ang);
            double c0 = cos(ang);
            double rot = (d < 256) ? -nrow[d + 256] : nrow[d - 256];
            rp[d] = (float)(nrow[d] * c0 + rot * s0);
        }
        __syncthreads();
    }
}

// ---------------- 3) Gram matrices, fp64 accumulate, double storage ----------
// z = b*3+m; m: 0->k^Tk, 1->k^Tq, 2->q^Tq
__global__ __launch_bounds__(256) void k_gram(const float* __restrict__ qbuf,
                                              const float* __restrict__ kbuf,
                                              double* __restrict__ G) {
    __shared__ float As[16][64], Bs[16][64];
    int tid = threadIdx.x, tx = tid & 15, ty = tid >> 4;
    int z = blockIdx.z;
    int b = z / 3, m = z % 3;
    const float* A  = ((m == 2) ? qbuf : kbuf) + (size_t)b * L_ * D_;
    const float* Bp = ((m == 0) ? kbuf : qbuf) + (size_t)b * L_ * D_;
    int m0 = blockIdx.y * 64, n0 = blockIdx.x * 64;
    double acc[4][4] = {};
    for (int k0 = 0; k0 < L_; k0 += 16) {
        load_KM(A,  D_, m0, k0, tid, As);
        load_KM(Bp, D_, n0, k0, tid, Bs);
        __syncthreads();
        mma16_ff(As, Bs, tx, ty, acc);
        __syncthreads();
    }
    double* Gg = G + (size_t)z * (512 * 512);
#pragma unroll
    for (int i = 0; i < 4; ++i)
#pragma unroll
        for (int j = 0; j < 4; ++j)
            Gg[(size_t)(m0 + (ty << 2) + i) * 512 + n0 + (tx << 2) + j] = acc[i][j];
}

// ---------------- 4) U = {q,q,k} @ G (double G), fp64 acc, fp32 store --------
__global__ __launch_bounds__(256) void k_u(const float* __restrict__ qbuf,
                                           const float* __restrict__ kbuf,
                                           const double* __restrict__ G,
                                           float* __restrict__ U) {
    __shared__ float As[16][64];
    __shared__ double Bs[16][64];
    int tid = threadIdx.x, tx = tid & 15, ty = tid >> 4;
    int z = blockIdx.z;                 // b*3+m
    int b = z / 3, m = z % 3;
    const float* A  = ((m == 2) ? kbuf : qbuf) + (size_t)b * L_ * D_;
    const double* Bp = G + (size_t)z * (512 * 512);
    int m0 = blockIdx.y * 64, n0 = blockIdx.x * 64;
    double acc[4][4] = {};
    for (int k0 = 0; k0 < D_; k0 += 16) {
        load_MK(A, D_, m0, k0, tid, As);
        load_KM_d(Bp, 512, n0, k0, tid, Bs);
        __syncthreads();
        mma16_fd(As, Bs, tx, ty, acc);
        __syncthreads();
    }
    float* Uo = U + (size_t)z * ((size_t)L_ * D_);
#pragma unroll
    for (int i = 0; i < 4; ++i)
#pragma unroll
        for (int j = 0; j < 4; ++j)
            Uo[(size_t)(m0 + (ty << 2) + i) * D_ + n0 + (tx << 2) + j] = (float)acc[i][j];
}

// ---------------- 5) raw scores = U @ {q,k,k}^T, fp64 acc, fp32 out ----------
__global__ __launch_bounds__(256) void k_scores(const float* __restrict__ qbuf,
                                                const float* __restrict__ kbuf,
                                                const float* __restrict__ U,
                                                float* __restrict__ out) {
    __shared__ float As[16][64], Bs[16][64];
    int tid = threadIdx.x, tx = tid & 15, ty = tid >> 4;
    int z = blockIdx.z;                 // b*3+m
    int b = z / 3, m = z % 3;
    const float* A  = U + (size_t)z * ((size_t)L_ * D_);
    const float* Bp = ((m == 0) ? qbuf : kbuf) + (size_t)b * L_ * D_;
    int m0 = blockIdx.y * 64, n0 = blockIdx.x * 64;
    double acc[4][4] = {};
    for (int k0 = 0; k0 < D_; k0 += 16) {
        load_MK(A,  D_, m0, k0, tid, As);
        load_MK(Bp, D_, n0, k0, tid, Bs);
        __syncthreads();
        mma16_ff(As, Bs, tx, ty, acc);
        __syncthreads();
    }
    float* Co = out + (size_t)(1 + m) * SLOT + (size_t)b * LL;
#pragma unroll
    for (int i = 0; i < 4; ++i)
#pragma unroll
        for (int j = 0; j < 4; ++j)
            Co[(size_t)(m0 + (ty << 2) + i) * L_ + n0 + (tx << 2) + j] = (float)acc[i][j];
}

// ---------------- 6) entmax-1.5 per row, fp64 bisection, in place ------------
__global__ __launch_bounds__(256) void k_entmax(float* __restrict__ base, int nrows,
                                                const float* __restrict__ wC,
                                                const float* __restrict__ wF,
                                                const float* __restrict__ wS,
                                                int clip) {
    int tid = threadIdx.x;
    int lane = tid & 63;
    int r = blockIdx.x * 4 + (tid >> 6);
    if (r >= nrows) return;
    double w = 1.0;
    if (wC) {
        int m = r >> 12;                 // 4096 rows per matrix
        const float* wp = (m == 0) ? wC : (m == 1) ? wF : wS;
        w = 2.0 / (1.0 + exp(-(double)wp[0]));
    }
    float* row = base + (size_t)r * L_;
    double z[32];
    double mx = -1.0e300;
#pragma unroll
    for (int j = 0; j < 32; ++j) {
        z[j] = 0.5 * w * (double)row[lane + (j << 6)];
        mx = fmax(mx, z[j]);
    }
    for (int off = 32; off; off >>= 1) mx = fmax(mx, __shfl_xor(mx, off));
#pragma unroll
    for (int j = 0; j < 32; ++j) z[j] -= mx;
    double lo = -1.0, hi = 0.0;
    for (int it = 0; it < 50; ++it) {
        double tau = 0.5 * (lo + hi);
        double ssum = 0.0;
#pragma unroll
        for (int j = 0; j < 32; ++j) {
            double t = fmax(z[j] - tau, 0.0);
            ssum = fma(t, t, ssum);
        }
        for (int off = 32; off; off >>= 1) ssum += __shfl_xor(ssum, off);
        if (ssum >= 1.0) lo = tau; else hi = tau;
    }
    double tau = 0.5 * (lo + hi);
#pragma unroll
    for (int j = 0; j < 32; ++j) {
        double t = fmax(z[j] - tau, 0.0);
        double p = t * t;
        if (clip) p = fmin(p, 1.0 - 1e-6);
        row[lane + (j << 6)] = (float)p;
    }
}

// ---------------- 7) column sums (deterministic, fp64, no atomics) -----------
__global__ __launch_bounds__(256) void k_colsum(const float* __restrict__ out,
                                                double* __restrict__ csC,
                                                double* __restrict__ csS) {
    int which = blockIdx.z >> 1, b = blockIdx.z & 1;
    const float* mat = out + (size_t)(which ? 3 : 1) * SLOT + (size_t)b * LL;
    int j = blockIdx.x * 256 + threadIdx.x;
    double s = 0.0;
#pragma unroll 8
    for (int r = 0; r < L_; ++r) s += (double)mat[(size_t)r * L_ + j];
    (which ? csS : csC)[b * L_ + j] = s;
}

// ---------------- 8) finalize p's, build H (fp64 math) -----------------------
__global__ __launch_bounds__(256) void k_finalize(float* __restrict__ out,
                                                  const double* __restrict__ csC,
                                                  const double* __restrict__ csS) {
    int row = blockIdx.x;               // b*2048 + i
    int i = row & (L_ - 1), b = row >> 11;
    size_t ro = (size_t)row * L_;
    float* H  = out + ro;
    float* pC = out + SLOT + ro;
    float* pF = out + 2 * SLOT + ro;
    float* pS = out + 3 * SLOT + ro;
    const double* cc = csC + b * L_;
    const double* cs = csS + b * L_;
    const double A1 = 1.0 - 2e-6;
    for (int j = threadIdx.x; j < L_; j += 256) {
        double c = (double)pC[j] * rsqrt(cc[j] + 1e-6);
        double f = (double)pF[j];
        double s = (double)pS[j] * rsqrt(cs[j] + 1e-6);
        c = fmax(A1 * c + 1e-6, 1e-6);
        f = fmax(A1 * f + 1e-6, 1e-6);
        s = fmax(A1 * s + 1e-6, 1e-6);
        pC[j] = (float)c; pF[j] = (float)f; pS[j] = (float)s;
        H[j] = (j == i) ? -1e9f : (float)((log(c) + log(f) + log(s)) * (1.0 / 3.0));
    }
}

// ---------------- launch -----------------------------------------------------
extern "C" void kernel_launch(void* const* d_in, const int* in_sizes, int n_in,
                              void* d_out, int out_size, void* d_ws, size_t ws_size,
                              hipStream_t stream) {
    const float* x  = (const float*)d_in[0];
    const float* Wq = (const float*)d_in[1];
    const float* Wk = (const float*)d_in[2];
    const float* qg = (const float*)d_in[3];
    const float* qb = (const float*)d_in[4];
    const float* kg = (const float*)d_in[5];
    const float* kb = (const float*)d_in[6];
    const float* wC = (const float*)d_in[7];
    const float* wF = (const float*)d_in[8];
    const float* wS = (const float*)d_in[9];
    float* out = (float*)d_out;

    // workspace carve (double region first for alignment)
    char* wsb = (char*)d_ws;
    double* Gd   = (double*)wsb;                      wsb += G_N * sizeof(double);      // 12.6 MB
    double* csC  = (double*)wsb;                      wsb += (size_t)B_ * L_ * sizeof(double);
    double* csS  = (double*)wsb;                      wsb += (size_t)B_ * L_ * sizeof(double);
    float*  qbuf = (float*)wsb;                       wsb += QK_N * sizeof(float);      // 8.4 MB
    float*  kbuf = (float*)wsb;                       wsb += QK_N * sizeof(float);      // 8.4 MB
    float*  Ubuf = (float*)wsb;                       /* 25.2 MB */

    k_proj    <<<dim3(8, 64, 2),  256, 0, stream>>>(x, Wq, Wk, qbuf, kbuf);
    k_lnrope  <<<dim3(B_ * L_),   128, 0, stream>>>(qbuf, kbuf, qg, qb, kg, kb);
    k_gram    <<<dim3(8, 8, 6),   256, 0, stream>>>(qbuf, kbuf, Gd);
    k_u       <<<dim3(8, 32, 6),  256, 0, stream>>>(qbuf, kbuf, Gd, Ubuf);
    k_scores  <<<dim3(32, 32, 6), 256, 0, stream>>>(qbuf, kbuf, Ubuf, out);
    k_entmax  <<<dim3(3072),      256, 0, stream>>>(out + SLOT, 3 * B_ * L_, wC, wF, wS, 1);
    k_colsum  <<<dim3(8, 1, 4),   256, 0, stream>>>(out, csC, csS);
    k_finalize<<<dim3(B_ * L_),   256, 0, stream>>>(out, csC, csS);
    k_entmax  <<<dim3(1024),      256, 0, stream>>>(out, B_ * L_, nullptr, nullptr, nullptr, 0);
}

// Round 4
// 1278.623 us; speedup vs baseline: 1.3384x; 1.3384x over previous
//
#include <hip/hip_runtime.h>
#include <cstddef>
#include <math.h>

// ---------------- problem constants ----------------
#define B_   2
#define L_   2048
#define D_   512
#define E_   768
static const size_t LL   = (size_t)L_ * L_;     // 4194304 per batch
static const size_t SLOT = (size_t)B_ * LL;     // 8388608 per output slot

#define QK_N   ((size_t)B_ * L_ * D_)      // 2097152 floats
#define G_N    ((size_t)6 * 512 * 512)     // 1572864 floats
#define U_N    ((size_t)6 * L_ * D_)       // 6291456 floats

typedef unsigned short u16;
typedef __attribute__((ext_vector_type(8))) short short8;   // 8 bf16 (4 VGPR)
typedef __attribute__((ext_vector_type(4))) float f32x4;

// ---------------- bf16x3 exact split of fp32 ---------------------------------
__device__ __forceinline__ u16 f2bf(float f) {
    unsigned x = __float_as_uint(f);
    unsigned r = (x + 0x7fffu + ((x >> 16) & 1u)) >> 16;    // RNE
    return (u16)r;
}
__device__ __forceinline__ float bf2f(u16 h) { return __uint_as_float(((unsigned)h) << 16); }
__device__ __forceinline__ void split3(float f, u16& h0, u16& h1, u16& h2) {
    h0 = f2bf(f); float r = f - bf2f(h0);
    h1 = f2bf(r); r -= bf2f(h1);
    h2 = f2bf(r);                                            // exact: fp32 = h0+h1+h2
}

// ---------------- MFMA GEMM: 64x64 tile, BK=32, bf16x3 8-tier ----------------
#define BKP 40   // padded LDS row (ushorts): 80 B, 16B-aligned frag reads, ~2-way banks

// stage [M x K] row-major (k contiguous) source into S[split][m][k]
__device__ __forceinline__ void stage_MK(const float* __restrict__ P, int ld,
                                         int r0, int k0, int tid, u16 S[3][64][BKP]) {
#pragma unroll
    for (int i = 0; i < 2; ++i) {
        int f = tid + i * 256;
        int m = f >> 3, kq = (f & 7) << 2;
        float4 v = *reinterpret_cast<const float4*>(P + (size_t)(r0 + m) * ld + k0 + kq);
        float vv[4] = {v.x, v.y, v.z, v.w};
        u16 h[3][4];
#pragma unroll
        for (int c = 0; c < 4; ++c) split3(vv[c], h[0][c], h[1][c], h[2][c]);
#pragma unroll
        for (int s = 0; s < 3; ++s)
            *reinterpret_cast<ushort4*>(&S[s][m][kq]) = make_ushort4(h[s][0], h[s][1], h[s][2], h[s][3]);
    }
}

// stage [K x M] row-major (m contiguous) source into S[split][m][k] (transpose)
__device__ __forceinline__ void stage_KM(const float* __restrict__ P, int ld,
                                         int r0, int k0, int tid, u16 S[3][64][BKP]) {
#pragma unroll
    for (int i = 0; i < 2; ++i) {
        int f = tid + i * 256;
        int k = f >> 4, mq = (f & 15) << 2;
        float4 v = *reinterpret_cast<const float4*>(P + (size_t)(k0 + k) * ld + r0 + mq);
        float vv[4] = {v.x, v.y, v.z, v.w};
#pragma unroll
        for (int c = 0; c < 4; ++c) {
            u16 h0, h1, h2; split3(vv[c], h0, h1, h2);
            S[0][mq + c][k] = h0; S[1][mq + c][k] = h1; S[2][mq + c][k] = h2;
        }
    }
}

// 256 threads = 4 waves in 2x2; each wave 32x32 = 2x2 frags of 16x16.
// Tier banks: H = hi*hi (promoted to fp64 every 2 K-steps), M = 2^-8 tier,
// L = 2^-16 and 2^-24 tiers. Dropped: lo*lo (2^-32) only.
template<bool AKM, bool BKM>
__device__ __forceinline__ void gemm_body(const float* __restrict__ A, int lda,
                                          const float* __restrict__ Bm, int ldb,
                                          float* __restrict__ C, int ldc,
                                          int K, int m0, int n0) {
    __shared__ u16 SA[3][64][BKP], SB[3][64][BKP];
    int tid = threadIdx.x;
    f32x4 accH[2][2], accM[2][2], accL[2][2];
#pragma unroll
    for (int i = 0; i < 2; ++i)
#pragma unroll
        for (int j = 0; j < 2; ++j) {
            accH[i][j] = (f32x4){0.f, 0.f, 0.f, 0.f};
            accM[i][j] = (f32x4){0.f, 0.f, 0.f, 0.f};
            accL[i][j] = (f32x4){0.f, 0.f, 0.f, 0.f};
        }
    double accD[2][2][4] = {};

    int lane = tid & 63, w = tid >> 6;
    int wm = (w & 1) << 5, wn = (w >> 1) << 5;
    int fr = lane & 15, ko = (lane >> 4) << 3;

    int nstep = K >> 5;
    for (int s = 0; s < nstep; ++s) {
        int k0 = s << 5;
        if (AKM) stage_KM(A, lda, m0, k0, tid, SA); else stage_MK(A, lda, m0, k0, tid, SA);
        if (BKM) stage_KM(Bm, ldb, n0, k0, tid, SB); else stage_MK(Bm, ldb, n0, k0, tid, SB);
        __syncthreads();

        short8 a[2][3], b[2][3];
#pragma unroll
        for (int f = 0; f < 2; ++f)
#pragma unroll
            for (int sp = 0; sp < 3; ++sp) {
                a[f][sp] = *reinterpret_cast<const short8*>(&SA[sp][wm + f * 16 + fr][ko]);
                b[f][sp] = *reinterpret_cast<const short8*>(&SB[sp][wn + f * 16 + fr][ko]);
            }
#pragma unroll
        for (int fi = 0; fi < 2; ++fi)
#pragma unroll
            for (int fj = 0; fj < 2; ++fj) {
                accH[fi][fj] = __builtin_amdgcn_mfma_f32_16x16x32_bf16(a[fi][0], b[fj][0], accH[fi][fj], 0, 0, 0);
                accM[fi][fj] = __builtin_amdgcn_mfma_f32_16x16x32_bf16(a[fi][0], b[fj][1], accM[fi][fj], 0, 0, 0);
                accM[fi][fj] = __builtin_amdgcn_mfma_f32_16x16x32_bf16(a[fi][1], b[fj][0], accM[fi][fj], 0, 0, 0);
                accL[fi][fj] = __builtin_amdgcn_mfma_f32_16x16x32_bf16(a[fi][0], b[fj][2], accL[fi][fj], 0, 0, 0);
                accL[fi][fj] = __builtin_amdgcn_mfma_f32_16x16x32_bf16(a[fi][1], b[fj][1], accL[fi][fj], 0, 0, 0);
                accL[fi][fj] = __builtin_amdgcn_mfma_f32_16x16x32_bf16(a[fi][2], b[fj][0], accL[fi][fj], 0, 0, 0);
                accL[fi][fj] = __builtin_amdgcn_mfma_f32_16x16x32_bf16(a[fi][1], b[fj][2], accL[fi][fj], 0, 0, 0);
                accL[fi][fj] = __builtin_amdgcn_mfma_f32_16x16x32_bf16(a[fi][2], b[fj][1], accL[fi][fj], 0, 0, 0);
            }
        __syncthreads();

        if (s & 1) {   // promote hi*hi chunk (K=64) to fp64
#pragma unroll
            for (int fi = 0; fi < 2; ++fi)
#pragma unroll
                for (int fj = 0; fj < 2; ++fj) {
#pragma unroll
                    for (int r = 0; r < 4; ++r) accD[fi][fj][r] += (double)accH[fi][fj][r];
                    accH[fi][fj] = (f32x4){0.f, 0.f, 0.f, 0.f};
                }
        }
    }
    // epilogue: C layout col=lane&15, row=(lane>>4)*4+reg  [m89-verified]
    int col = lane & 15, rbase = (lane >> 4) << 2;
#pragma unroll
    for (int fi = 0; fi < 2; ++fi)
#pragma unroll
        for (int fj = 0; fj < 2; ++fj)
#pragma unroll
            for (int r = 0; r < 4; ++r) {
                double v = accD[fi][fj][r] + (double)accH[fi][fj][r]
                         + (double)accM[fi][fj][r] + (double)accL[fi][fj][r];
                int mm = m0 + wm + fi * 16 + rbase + r;
                int nn = n0 + wn + fj * 16 + col;
                C[(size_t)mm * ldc + nn] = (float)v;
            }
}

// ---------------- MFMA GEMM instantiations -----------------------------------
__global__ __launch_bounds__(256) void k_proj(const float* __restrict__ x,
                                              const float* __restrict__ Wq,
                                              const float* __restrict__ Wk,
                                              float* __restrict__ qbuf,
                                              float* __restrict__ kbuf) {
    const float* W = blockIdx.z ? Wk : Wq;
    float* out = blockIdx.z ? kbuf : qbuf;
    gemm_body<false, false>(x, E_, W, E_, out, D_, E_, blockIdx.y * 64, blockIdx.x * 64);
}

// z = b*3+m; m: 0->k^Tk, 1->k^Tq, 2->q^Tq; both operands [L x D] = K-major
__global__ __launch_bounds__(256) void k_gram(const float* __restrict__ qbuf,
                                              const float* __restrict__ kbuf,
                                              float* __restrict__ G) {
    int z = blockIdx.z, b = z / 3, m = z % 3;
    const float* A  = ((m == 2) ? qbuf : kbuf) + (size_t)b * L_ * D_;
    const float* Bp = ((m == 0) ? kbuf : qbuf) + (size_t)b * L_ * D_;
    float* Cg = G + (size_t)z * (512 * 512);
    gemm_body<true, true>(A, D_, Bp, D_, Cg, 512, L_, blockIdx.y * 64, blockIdx.x * 64);
}

__global__ __launch_bounds__(256) void k_scores(const float* __restrict__ qbuf,
                                                const float* __restrict__ kbuf,
                                                const float* __restrict__ U,
                                                float* __restrict__ out) {
    int z = blockIdx.z, b = z / 3, m = z % 3;
    const float* A  = U + (size_t)z * ((size_t)L_ * D_);
    const float* Bp = ((m == 0) ? qbuf : kbuf) + (size_t)b * L_ * D_;
    float* Co = out + (size_t)(1 + m) * SLOT + (size_t)b * LL;
    gemm_body<false, false>(A, D_, Bp, D_, Co, L_, D_, blockIdx.y * 64, blockIdx.x * 64);
}

// ---------------- k_u: fp64-VALU (U is a high-amplification intermediate) ----
__device__ __forceinline__ void load_MKf(const float* __restrict__ A, int lda,
                                         int m0, int k0, int tid, float S[16][64]) {
    int mi = tid >> 2;
    int kj = (tid & 3) << 2;
    const float4 v = *reinterpret_cast<const float4*>(A + (size_t)(m0 + mi) * lda + (k0 + kj));
    S[kj + 0][mi] = v.x; S[kj + 1][mi] = v.y; S[kj + 2][mi] = v.z; S[kj + 3][mi] = v.w;
}
__device__ __forceinline__ void load_KMf(const float* __restrict__ A, int lda,
                                         int m0, int k0, int tid, float S[16][64]) {
    int kj = tid >> 4;
    int mi = (tid & 15) << 2;
    *reinterpret_cast<float4*>(&S[kj][mi]) =
        *reinterpret_cast<const float4*>(A + (size_t)(k0 + kj) * lda + (m0 + mi));
}
__device__ __forceinline__ void mma16_ff(float SA[16][64], float SB[16][64],
                                         int tx, int ty, double acc[4][4]) {
#pragma unroll
    for (int kk = 0; kk < 16; ++kk) {
        float4 a = *reinterpret_cast<float4*>(&SA[kk][ty << 2]);
        float4 b = *reinterpret_cast<float4*>(&SB[kk][tx << 2]);
        double av[4] = {(double)a.x, (double)a.y, (double)a.z, (double)a.w};
        double bv[4] = {(double)b.x, (double)b.y, (double)b.z, (double)b.w};
#pragma unroll
        for (int i = 0; i < 4; ++i)
#pragma unroll
            for (int j = 0; j < 4; ++j)
                acc[i][j] = fma(av[i], bv[j], acc[i][j]);
    }
}

__global__ __launch_bounds__(256) void k_u(const float* __restrict__ qbuf,
                                           const float* __restrict__ kbuf,
                                           const float* __restrict__ G,
                                           float* __restrict__ U) {
    __shared__ float As[16][64], Bs[16][64];
    int tid = threadIdx.x, tx = tid & 15, ty = tid >> 4;
    int z = blockIdx.z, b = z / 3, m = z % 3;
    const float* A  = ((m == 2) ? kbuf : qbuf) + (size_t)b * L_ * D_;
    const float* Bp = G + (size_t)z * (512 * 512);
    int m0 = blockIdx.y * 64, n0 = blockIdx.x * 64;
    double acc[4][4] = {};
    for (int k0 = 0; k0 < D_; k0 += 16) {
        load_MKf(A, D_, m0, k0, tid, As);
        load_KMf(Bp, 512, n0, k0, tid, Bs);
        __syncthreads();
        mma16_ff(As, Bs, tx, ty, acc);
        __syncthreads();
    }
    float* Uo = U + (size_t)z * ((size_t)L_ * D_);
#pragma unroll
    for (int i = 0; i < 4; ++i)
#pragma unroll
        for (int j = 0; j < 4; ++j)
            Uo[(size_t)(m0 + (ty << 2) + i) * D_ + n0 + (tx << 2) + j] = (float)acc[i][j];
}

// ---------------- LayerNorm + RoPE, fp64 math, shared trig table -------------
__global__ __launch_bounds__(128) void k_lnrope(float* qbuf, float* kbuf,
                                                const float* __restrict__ qg, const float* __restrict__ qb,
                                                const float* __restrict__ kg, const float* __restrict__ kb) {
    int row = blockIdx.x;           // b*2048 + l
    int l = row & (L_ - 1);
    int tid = threadIdx.x;
    __shared__ double nrow[D_];
    __shared__ double red[4];
    __shared__ double cs_[256], sn_[256];
    for (int j = tid; j < 256; j += 128) {
        double e = (double)j * (1.0 / 256.0);
        double inv = pow(10000.0, -e);
        double ang = (double)l * inv;
        cs_[j] = cos(ang); sn_[j] = sin(ang);
    }
    __syncthreads();
    for (int pass = 0; pass < 2; ++pass) {
        float* buf = pass ? kbuf : qbuf;
        const float* g  = pass ? kg : qg;
        const float* bt = pass ? kb : qb;
        float* rp = buf + (size_t)row * D_;
        float4 v = reinterpret_cast<float4*>(rp)[tid];
        double vv[4] = {(double)v.x, (double)v.y, (double)v.z, (double)v.w};
        double s = vv[0] + vv[1] + vv[2] + vv[3];
        double s2 = vv[0]*vv[0] + vv[1]*vv[1] + vv[2]*vv[2] + vv[3]*vv[3];
        for (int off = 32; off; off >>= 1) { s += __shfl_xor(s, off); s2 += __shfl_xor(s2, off); }
        int wv = tid >> 6;
        if ((tid & 63) == 0) { red[wv * 2] = s; red[wv * 2 + 1] = s2; }
        __syncthreads();
        double mu  = (red[0] + red[2]) * (1.0 / D_);
        double var = (red[1] + red[3]) * (1.0 / D_) - mu * mu;
        double rs = rsqrt(var + 1e-5);
        int d0 = tid * 4;
        double o[4];
#pragma unroll
        for (int c = 0; c < 4; ++c) {
            int d = d0 + c;
            o[c] = (vv[c] - mu) * rs * (double)g[d] + (double)bt[d];
        }
        __syncthreads();
#pragma unroll
        for (int c = 0; c < 4; ++c) nrow[d0 + c] = o[c];
        __syncthreads();
#pragma unroll
        for (int c = 0; c < 4; ++c) {
            int d = d0 + c;
            double rot = (d < 256) ? -nrow[d + 256] : nrow[d - 256];
            rp[d] = (float)(nrow[d] * cs_[d & 255] + rot * sn_[d & 255]);
        }
        __syncthreads();
    }
}

// ---------------- entmax-1.5 per row, fp64 bisection, in place ---------------
__global__ __launch_bounds__(256) void k_entmax(float* __restrict__ base, int nrows,
                                                const float* __restrict__ wC,
                                                const float* __restrict__ wF,
                                                const float* __restrict__ wS,
                                                int clip) {
    int tid = threadIdx.x;
    int lane = tid & 63;
    int r = blockIdx.x * 4 + (tid >> 6);
    if (r >= nrows) return;
    double w = 1.0;
    if (wC) {
        int m = r >> 12;                 // 4096 rows per matrix
        const float* wp = (m == 0) ? wC : (m == 1) ? wF : wS;
        w = 2.0 / (1.0 + exp(-(double)wp[0]));
    }
    float* row = base + (size_t)r * L_;
    double z[32];
    double mx = -1.0e300;
#pragma unroll
    for (int j = 0; j < 32; ++j) {
        z[j] = 0.5 * w * (double)row[lane + (j << 6)];
        mx = fmax(mx, z[j]);
    }
    for (int off = 32; off; off >>= 1) mx = fmax(mx, __shfl_xor(mx, off));
#pragma unroll
    for (int j = 0; j < 32; ++j) z[j] -= mx;
    double lo = -1.0, hi = 0.0;
    for (int it = 0; it < 50; ++it) {
        double tau = 0.5 * (lo + hi);
        double ssum = 0.0;
#pragma unroll
        for (int j = 0; j < 32; ++j) {
            double t = fmax(z[j] - tau, 0.0);
            ssum = fma(t, t, ssum);
        }
        for (int off = 32; off; off >>= 1) ssum += __shfl_xor(ssum, off);
        if (ssum >= 1.0) lo = tau; else hi = tau;
    }
    double tau = 0.5 * (lo + hi);
#pragma unroll
    for (int j = 0; j < 32; ++j) {
        double t = fmax(z[j] - tau, 0.0);
        double p = t * t;
        if (clip) p = fmin(p, 1.0 - 1e-6);
        row[lane + (j << 6)] = (float)p;
    }
}

// ---------------- column sums (deterministic, fp64) --------------------------
__global__ __launch_bounds__(256) void k_colsum(const float* __restrict__ out,
                                                double* __restrict__ csC,
                                                double* __restrict__ csS) {
    int which = blockIdx.z >> 1, b = blockIdx.z & 1;
    const float* mat = out + (size_t)(which ? 3 : 1) * SLOT + (size_t)b * LL;
    int j = blockIdx.x * 256 + threadIdx.x;
    double s = 0.0;
#pragma unroll 8
    for (int r = 0; r < L_; ++r) s += (double)mat[(size_t)r * L_ + j];
    (which ? csS : csC)[b * L_ + j] = s;
}

// ---------------- finalize p's, build H (fp64 math) --------------------------
__global__ __launch_bounds__(256) void k_finalize(float* __restrict__ out,
                                                  const double* __restrict__ csC,
                                                  const double* __restrict__ csS) {
    int row = blockIdx.x;               // b*2048 + i
    int i = row & (L_ - 1), b = row >> 11;
    size_t ro = (size_t)row * L_;
    float* H  = out + ro;
    float* pC = out + SLOT + ro;
    float* pF = out + 2 * SLOT + ro;
    float* pS = out + 3 * SLOT + ro;
    const double* cc = csC + b * L_;
    const double* cs = csS + b * L_;
    const double A1 = 1.0 - 2e-6;
    for (int j = threadIdx.x; j < L_; j += 256) {
        double c = (double)pC[j] * rsqrt(cc[j] + 1e-6);
        double f = (double)pF[j];
        double s = (double)pS[j] * rsqrt(cs[j] + 1e-6);
        c = fmax(A1 * c + 1e-6, 1e-6);
        f = fmax(A1 * f + 1e-6, 1e-6);
        s = fmax(A1 * s + 1e-6, 1e-6);
        pC[j] = (float)c; pF[j] = (float)f; pS[j] = (float)s;
        H[j] = (j == i) ? -1e9f : (float)((log(c) + log(f) + log(s)) * (1.0 / 3.0));
    }
}

// ---------------- launch -----------------------------------------------------
extern "C" void kernel_launch(void* const* d_in, const int* in_sizes, int n_in,
                              void* d_out, int out_size, void* d_ws, size_t ws_size,
                              hipStream_t stream) {
    const float* x  = (const float*)d_in[0];
    const float* Wq = (const float*)d_in[1];
    const float* Wk = (const float*)d_in[2];
    const float* qg = (const float*)d_in[3];
    const float* qb = (const float*)d_in[4];
    const float* kg = (const float*)d_in[5];
    const float* kb = (const float*)d_in[6];
    const float* wC = (const float*)d_in[7];
    const float* wF = (const float*)d_in[8];
    const float* wS = (const float*)d_in[9];
    float* out = (float*)d_out;

    char* wsb = (char*)d_ws;
    double* csC  = (double*)wsb;  wsb += (size_t)B_ * L_ * sizeof(double);
    double* csS  = (double*)wsb;  wsb += (size_t)B_ * L_ * sizeof(double);
    float*  Gf   = (float*)wsb;   wsb += G_N * sizeof(float);    // 6.3 MB
    float*  qbuf = (float*)wsb;   wsb += QK_N * sizeof(float);   // 8.4 MB
    float*  kbuf = (float*)wsb;   wsb += QK_N * sizeof(float);   // 8.4 MB
    float*  Ubuf = (float*)wsb;                                  // 25.2 MB

    k_proj    <<<dim3(8, 64, 2),  256, 0, stream>>>(x, Wq, Wk, qbuf, kbuf);
    k_lnrope  <<<dim3(B_ * L_),   128, 0, stream>>>(qbuf, kbuf, qg, qb, kg, kb);
    k_gram    <<<dim3(8, 8, 6),   256, 0, stream>>>(qbuf, kbuf, Gf);
    k_u       <<<dim3(8, 32, 6),  256, 0, stream>>>(qbuf, kbuf, Gf, Ubuf);
    k_scores  <<<dim3(32, 32, 6), 256, 0, stream>>>(qbuf, kbuf, Ubuf, out);
    k_entmax  <<<dim3(3072),      256, 0, stream>>>(out + SLOT, 3 * B_ * L_, wC, wF, wS, 1);
    k_colsum  <<<dim3(8, 1, 4),   256, 0, stream>>>(out, csC, csS);
    k_finalize<<<dim3(B_ * L_),   256, 0, stream>>>(out, csC, csS);
    k_entmax  <<<dim3(1024),      256, 0, stream>>>(out, B_ * L_, nullptr, nullptr, nullptr, 0);
}

// Round 5
// 1040.806 us; speedup vs baseline: 1.6442x; 1.2285x over previous
//
#include <hip/hip_runtime.h>
#include <cstddef>
#include <math.h>

// ---------------- problem constants ----------------
#define B_   2
#define L_   2048
#define D_   512
#define E_   768
static const size_t LL   = (size_t)L_ * L_;
static const size_t SLOT = (size_t)B_ * LL;

#define QK_N  ((size_t)B_ * L_ * D_)       // 2097152
#define G1_N  ((size_t)512 * 512)          // 262144
#define G_N   ((size_t)6 * G1_N)           // 1572864
#define U_N   ((size_t)6 * L_ * D_)        // 6291456

typedef unsigned short u16;
typedef __attribute__((ext_vector_type(8))) short short8;   // 8 bf16
typedef __attribute__((ext_vector_type(4))) float f32x4;

// ---------------- bf16x3 exact split of fp32 ---------------------------------
__device__ __forceinline__ u16 f2bf(float f) {
    unsigned x = __float_as_uint(f);
    unsigned r = (x + 0x7fffu + ((x >> 16) & 1u)) >> 16;    // RNE
    return (u16)r;
}
__device__ __forceinline__ float bf2f(u16 h) { return __uint_as_float(((unsigned)h) << 16); }
__device__ __forceinline__ void split3(float f, u16& h0, u16& h1, u16& h2) {
    h0 = f2bf(f); float r = f - bf2f(h0);
    h1 = f2bf(r); r -= bf2f(h1);
    h2 = f2bf(r);                                            // exact: fp32 = h0+h1+h2
}

#define BKP 40   // LDS row pitch in u16

// ============ plane-based stagers (no conversion math) ========================
// MK: plane rows [R x ld] row-major, k contiguous
__device__ __forceinline__ void pstage_MK(const u16* __restrict__ P, size_t pstride, int ld,
                                          int r0, int k0, int tid, u16 S[3][64][BKP]) {
    int m = tid >> 2, kq = (tid & 3) << 3;
#pragma unroll
    for (int s = 0; s < 3; ++s) {
        const u16* src = P + (size_t)s * pstride + (size_t)(r0 + m) * ld + k0 + kq;
        ushort4 v0 = *reinterpret_cast<const ushort4*>(src);
        ushort4 v1 = *reinterpret_cast<const ushort4*>(src + 4);
        *reinterpret_cast<ushort4*>(&S[s][m][kq]) = v0;
        *reinterpret_cast<ushort4*>(&S[s][m][kq + 4]) = v1;
    }
}
// KM: plane rows [K x ld] row-major, m contiguous -> transpose into S[m][k]
__device__ __forceinline__ void pstage_KM(const u16* __restrict__ P, size_t pstride, int ld,
                                          int r0, int k0, int tid, u16 S[3][64][BKP]) {
    int k = tid >> 3, mq = (tid & 7) << 3;
#pragma unroll
    for (int s = 0; s < 3; ++s) {
        const u16* src = P + (size_t)s * pstride + (size_t)(k0 + k) * ld + r0 + mq;
        ushort4 v0 = *reinterpret_cast<const ushort4*>(src);
        ushort4 v1 = *reinterpret_cast<const ushort4*>(src + 4);
        S[s][mq + 0][k] = v0.x; S[s][mq + 1][k] = v0.y; S[s][mq + 2][k] = v0.z; S[s][mq + 3][k] = v0.w;
        S[s][mq + 4][k] = v1.x; S[s][mq + 5][k] = v1.y; S[s][mq + 6][k] = v1.z; S[s][mq + 7][k] = v1.w;
    }
}

// ============ shared 8-tier bf16x3 MFMA core (64x64 tile, BK=32) ==============
// H tier promoted to fp64 every K=32 step.
template<bool AKM, bool BKM>
__device__ __forceinline__ void gemm_core(const u16* __restrict__ Ap, size_t Aps, int lda,
                                          const u16* __restrict__ Bp, size_t Bps, int ldb,
                                          int K, int m0, int n0, int tid,
                                          double outv[2][2][4]) {
    __shared__ u16 SA[3][64][BKP], SB[3][64][BKP];
    f32x4 accH[2][2], accM[2][2], accL[2][2];
#pragma unroll
    for (int i = 0; i < 2; ++i)
#pragma unroll
        for (int j = 0; j < 2; ++j) {
            accH[i][j] = (f32x4){0.f, 0.f, 0.f, 0.f};
            accM[i][j] = (f32x4){0.f, 0.f, 0.f, 0.f};
            accL[i][j] = (f32x4){0.f, 0.f, 0.f, 0.f};
        }
    double accD[2][2][4] = {};
    int lane = tid & 63, w = tid >> 6;
    int wm = (w & 1) << 5, wn = (w >> 1) << 5;
    int fr = lane & 15, ko = (lane >> 4) << 3;

    int nstep = K >> 5;
    for (int s = 0; s < nstep; ++s) {
        int k0 = s << 5;
        if (AKM) pstage_KM(Ap, Aps, lda, m0, k0, tid, SA); else pstage_MK(Ap, Aps, lda, m0, k0, tid, SA);
        if (BKM) pstage_KM(Bp, Bps, ldb, n0, k0, tid, SB); else pstage_MK(Bp, Bps, ldb, n0, k0, tid, SB);
        __syncthreads();
        short8 a[2][3], b[2][3];
#pragma unroll
        for (int f = 0; f < 2; ++f)
#pragma unroll
            for (int sp = 0; sp < 3; ++sp) {
                a[f][sp] = *reinterpret_cast<const short8*>(&SA[sp][wm + f * 16 + fr][ko]);
                b[f][sp] = *reinterpret_cast<const short8*>(&SB[sp][wn + f * 16 + fr][ko]);
            }
#pragma unroll
        for (int fi = 0; fi < 2; ++fi)
#pragma unroll
            for (int fj = 0; fj < 2; ++fj) {
                accH[fi][fj] = __builtin_amdgcn_mfma_f32_16x16x32_bf16(a[fi][0], b[fj][0], accH[fi][fj], 0, 0, 0);
                accM[fi][fj] = __builtin_amdgcn_mfma_f32_16x16x32_bf16(a[fi][0], b[fj][1], accM[fi][fj], 0, 0, 0);
                accM[fi][fj] = __builtin_amdgcn_mfma_f32_16x16x32_bf16(a[fi][1], b[fj][0], accM[fi][fj], 0, 0, 0);
                accL[fi][fj] = __builtin_amdgcn_mfma_f32_16x16x32_bf16(a[fi][0], b[fj][2], accL[fi][fj], 0, 0, 0);
                accL[fi][fj] = __builtin_amdgcn_mfma_f32_16x16x32_bf16(a[fi][1], b[fj][1], accL[fi][fj], 0, 0, 0);
                accL[fi][fj] = __builtin_amdgcn_mfma_f32_16x16x32_bf16(a[fi][2], b[fj][0], accL[fi][fj], 0, 0, 0);
                accL[fi][fj] = __builtin_amdgcn_mfma_f32_16x16x32_bf16(a[fi][1], b[fj][2], accL[fi][fj], 0, 0, 0);
                accL[fi][fj] = __builtin_amdgcn_mfma_f32_16x16x32_bf16(a[fi][2], b[fj][1], accL[fi][fj], 0, 0, 0);
            }
        __syncthreads();
#pragma unroll
        for (int fi = 0; fi < 2; ++fi)
#pragma unroll
            for (int fj = 0; fj < 2; ++fj) {
#pragma unroll
                for (int r = 0; r < 4; ++r) accD[fi][fj][r] += (double)accH[fi][fj][r];
                accH[fi][fj] = (f32x4){0.f, 0.f, 0.f, 0.f};
            }
    }
#pragma unroll
    for (int fi = 0; fi < 2; ++fi)
#pragma unroll
        for (int fj = 0; fj < 2; ++fj)
#pragma unroll
            for (int r = 0; r < 4; ++r)
                outv[fi][fj][r] = accD[fi][fj][r] + (double)accM[fi][fj][r] + (double)accL[fi][fj][r];
}

// ============ k_proj: fp32 sources, split3 staging (round-4 proven path) ======
__device__ __forceinline__ void stage_MKf(const float* __restrict__ P, int ld,
                                          int r0, int k0, int tid, u16 S[3][64][BKP]) {
#pragma unroll
    for (int i = 0; i < 2; ++i) {
        int f = tid + i * 256;
        int m = f >> 3, kq = (f & 7) << 2;
        float4 v = *reinterpret_cast<const float4*>(P + (size_t)(r0 + m) * ld + k0 + kq);
        float vv[4] = {v.x, v.y, v.z, v.w};
        u16 h[3][4];
#pragma unroll
        for (int c = 0; c < 4; ++c) split3(vv[c], h[0][c], h[1][c], h[2][c]);
#pragma unroll
        for (int s = 0; s < 3; ++s)
            *reinterpret_cast<ushort4*>(&S[s][m][kq]) = make_ushort4(h[s][0], h[s][1], h[s][2], h[s][3]);
    }
}

__global__ __launch_bounds__(256) void k_proj(const float* __restrict__ x,
                                              const float* __restrict__ Wq,
                                              const float* __restrict__ Wk,
                                              float* __restrict__ qraw,
                                              float* __restrict__ kraw) {
    __shared__ u16 SA[3][64][BKP], SB[3][64][BKP];
    const float* W = blockIdx.z ? Wk : Wq;
    float* out = blockIdx.z ? kraw : qraw;
    int tid = threadIdx.x;
    int m0 = blockIdx.y * 64, n0 = blockIdx.x * 64;
    f32x4 accH[2][2], accM[2][2], accL[2][2];
#pragma unroll
    for (int i = 0; i < 2; ++i)
#pragma unroll
        for (int j = 0; j < 2; ++j) {
            accH[i][j] = (f32x4){0.f, 0.f, 0.f, 0.f};
            accM[i][j] = (f32x4){0.f, 0.f, 0.f, 0.f};
            accL[i][j] = (f32x4){0.f, 0.f, 0.f, 0.f};
        }
    double accD[2][2][4] = {};
    int lane = tid & 63, w = tid >> 6;
    int wm = (w & 1) << 5, wn = (w >> 1) << 5;
    int fr = lane & 15, ko = (lane >> 4) << 3;
    for (int s = 0; s < (E_ >> 5); ++s) {
        int k0 = s << 5;
        stage_MKf(x, E_, m0, k0, tid, SA);
        stage_MKf(W, E_, n0, k0, tid, SB);
        __syncthreads();
        short8 a[2][3], b[2][3];
#pragma unroll
        for (int f = 0; f < 2; ++f)
#pragma unroll
            for (int sp = 0; sp < 3; ++sp) {
                a[f][sp] = *reinterpret_cast<const short8*>(&SA[sp][wm + f * 16 + fr][ko]);
                b[f][sp] = *reinterpret_cast<const short8*>(&SB[sp][wn + f * 16 + fr][ko]);
            }
#pragma unroll
        for (int fi = 0; fi < 2; ++fi)
#pragma unroll
            for (int fj = 0; fj < 2; ++fj) {
                accH[fi][fj] = __builtin_amdgcn_mfma_f32_16x16x32_bf16(a[fi][0], b[fj][0], accH[fi][fj], 0, 0, 0);
                accM[fi][fj] = __builtin_amdgcn_mfma_f32_16x16x32_bf16(a[fi][0], b[fj][1], accM[fi][fj], 0, 0, 0);
                accM[fi][fj] = __builtin_amdgcn_mfma_f32_16x16x32_bf16(a[fi][1], b[fj][0], accM[fi][fj], 0, 0, 0);
                accL[fi][fj] = __builtin_amdgcn_mfma_f32_16x16x32_bf16(a[fi][0], b[fj][2], accL[fi][fj], 0, 0, 0);
                accL[fi][fj] = __builtin_amdgcn_mfma_f32_16x16x32_bf16(a[fi][1], b[fj][1], accL[fi][fj], 0, 0, 0);
                accL[fi][fj] = __builtin_amdgcn_mfma_f32_16x16x32_bf16(a[fi][2], b[fj][0], accL[fi][fj], 0, 0, 0);
                accL[fi][fj] = __builtin_amdgcn_mfma_f32_16x16x32_bf16(a[fi][1], b[fj][2], accL[fi][fj], 0, 0, 0);
                accL[fi][fj] = __builtin_amdgcn_mfma_f32_16x16x32_bf16(a[fi][2], b[fj][1], accL[fi][fj], 0, 0, 0);
            }
        __syncthreads();
        if (s & 1) {
#pragma unroll
            for (int fi = 0; fi < 2; ++fi)
#pragma unroll
                for (int fj = 0; fj < 2; ++fj) {
#pragma unroll
                    for (int r = 0; r < 4; ++r) accD[fi][fj][r] += (double)accH[fi][fj][r];
                    accH[fi][fj] = (f32x4){0.f, 0.f, 0.f, 0.f};
                }
        }
    }
    int col = lane & 15, rbase = (lane >> 4) << 2;
#pragma unroll
    for (int fi = 0; fi < 2; ++fi)
#pragma unroll
        for (int fj = 0; fj < 2; ++fj)
#pragma unroll
            for (int r = 0; r < 4; ++r) {
                double v = accD[fi][fj][r] + (double)accH[fi][fj][r]
                         + (double)accM[fi][fj][r] + (double)accL[fi][fj][r];
                int mm = m0 + wm + fi * 16 + rbase + r;
                int nn = n0 + wn + fj * 16 + col;
                out[(size_t)mm * D_ + nn] = (float)v;
            }
}

// ============ RoPE table (fp64, computed once per launch) =====================
__global__ __launch_bounds__(256) void k_trig(double* __restrict__ tg) {
    int l = blockIdx.x, j = threadIdx.x;
    double e = (double)j * (1.0 / 256.0);
    double inv = pow(10000.0, -e);
    double ang = (double)l * inv;
    tg[(size_t)l * 512 + j] = cos(ang);
    tg[(size_t)l * 512 + 256 + j] = sin(ang);
}

// ============ LayerNorm + RoPE (fp64) -> bf16x3 planes ========================
__global__ __launch_bounds__(128) void k_lnrope(const float* __restrict__ qraw,
                                                const float* __restrict__ kraw,
                                                const double* __restrict__ tg,
                                                const float* __restrict__ qg, const float* __restrict__ qb,
                                                const float* __restrict__ kg, const float* __restrict__ kb,
                                                u16* __restrict__ qP, u16* __restrict__ kP) {
    int row = blockIdx.x;           // b*2048 + l
    int l = row & (L_ - 1);
    int tid = threadIdx.x;
    __shared__ double nrow[D_];
    __shared__ double red[4];
    __shared__ double cs_[256], sn_[256];
    for (int j = tid; j < 256; j += 128) {
        cs_[j] = tg[(size_t)l * 512 + j];
        sn_[j] = tg[(size_t)l * 512 + 256 + j];
    }
    __syncthreads();
    for (int pass = 0; pass < 2; ++pass) {
        const float* rp = (pass ? kraw : qraw) + (size_t)row * D_;
        const float* g  = pass ? kg : qg;
        const float* bt = pass ? kb : qb;
        u16* P = pass ? kP : qP;
        float4 v = reinterpret_cast<const float4*>(rp)[tid];
        double vv[4] = {(double)v.x, (double)v.y, (double)v.z, (double)v.w};
        double s = vv[0] + vv[1] + vv[2] + vv[3];
        double s2 = vv[0]*vv[0] + vv[1]*vv[1] + vv[2]*vv[2] + vv[3]*vv[3];
        for (int off = 32; off; off >>= 1) { s += __shfl_xor(s, off); s2 += __shfl_xor(s2, off); }
        int wv = tid >> 6;
        if ((tid & 63) == 0) { red[wv * 2] = s; red[wv * 2 + 1] = s2; }
        __syncthreads();
        double mu  = (red[0] + red[2]) * (1.0 / D_);
        double var = (red[1] + red[3]) * (1.0 / D_) - mu * mu;
        double rs = rsqrt(var + 1e-5);
        int d0 = tid * 4;
        double o[4];
#pragma unroll
        for (int c = 0; c < 4; ++c) {
            int d = d0 + c;
            o[c] = (vv[c] - mu) * rs * (double)g[d] + (double)bt[d];
        }
        __syncthreads();
#pragma unroll
        for (int c = 0; c < 4; ++c) nrow[d0 + c] = o[c];
        __syncthreads();
        u16 h[3][4];
#pragma unroll
        for (int c = 0; c < 4; ++c) {
            int d = d0 + c;
            double rot = (d < 256) ? -nrow[d + 256] : nrow[d - 256];
            float ov = (float)(nrow[d] * cs_[d & 255] + rot * sn_[d & 255]);
            split3(ov, h[0][c], h[1][c], h[2][c]);
        }
        size_t off = (size_t)row * D_ + d0;
#pragma unroll
        for (int sp = 0; sp < 3; ++sp)
            *reinterpret_cast<ushort4*>(P + sp * QK_N + off) = make_ushort4(h[sp][0], h[sp][1], h[sp][2], h[sp][3]);
        __syncthreads();
    }
}

// ============ Gram: planes -> G planes ========================================
__global__ __launch_bounds__(256) void k_gram(const u16* __restrict__ qP,
                                              const u16* __restrict__ kP,
                                              u16* __restrict__ GP) {
    int z = blockIdx.z, b = z / 3, m = z % 3;
    const u16* A  = ((m == 2) ? qP : kP) + (size_t)b * L_ * D_;
    const u16* Bp = ((m == 0) ? kP : qP) + (size_t)b * L_ * D_;
    int m0 = blockIdx.y * 64, n0 = blockIdx.x * 64;
    double ov[2][2][4];
    gemm_core<true, true>(A, QK_N, D_, Bp, QK_N, D_, L_, m0, n0, threadIdx.x, ov);
    int lane = threadIdx.x & 63, w = threadIdx.x >> 6;
    int wm = (w & 1) << 5, wn = (w >> 1) << 5;
    int col = lane & 15, rbase = (lane >> 4) << 2;
#pragma unroll
    for (int fi = 0; fi < 2; ++fi)
#pragma unroll
        for (int fj = 0; fj < 2; ++fj)
#pragma unroll
            for (int r = 0; r < 4; ++r) {
                float gf = (float)ov[fi][fj][r];
                int mm = m0 + wm + fi * 16 + rbase + r;
                int nn = n0 + wn + fj * 16 + col;
                size_t off = (size_t)z * G1_N + (size_t)mm * 512 + nn;
                u16 h0, h1, h2; split3(gf, h0, h1, h2);
                GP[off] = h0; GP[G_N + off] = h1; GP[2 * G_N + off] = h2;
            }
}

// ============ U = {q,q,k} @ G : planes -> U planes ============================
__global__ __launch_bounds__(256) void k_u(const u16* __restrict__ qP,
                                           const u16* __restrict__ kP,
                                           const u16* __restrict__ GP,
                                           u16* __restrict__ UP) {
    int z = blockIdx.z, b = z / 3, m = z % 3;
    const u16* A  = ((m == 2) ? kP : qP) + (size_t)b * L_ * D_;
    const u16* Bp = GP + (size_t)z * G1_N;
    int m0 = blockIdx.y * 64, n0 = blockIdx.x * 64;
    double ov[2][2][4];
    gemm_core<false, true>(A, QK_N, D_, Bp, G_N, 512, D_, m0, n0, threadIdx.x, ov);
    int lane = threadIdx.x & 63, w = threadIdx.x >> 6;
    int wm = (w & 1) << 5, wn = (w >> 1) << 5;
    int col = lane & 15, rbase = (lane >> 4) << 2;
#pragma unroll
    for (int fi = 0; fi < 2; ++fi)
#pragma unroll
        for (int fj = 0; fj < 2; ++fj)
#pragma unroll
            for (int r = 0; r < 4; ++r) {
                float uf = (float)ov[fi][fj][r];
                int mm = m0 + wm + fi * 16 + rbase + r;
                int nn = n0 + wn + fj * 16 + col;
                size_t off = (size_t)z * ((size_t)L_ * D_) + (size_t)mm * D_ + nn;
                u16 h0, h1, h2; split3(uf, h0, h1, h2);
                UP[off] = h0; UP[U_N + off] = h1; UP[2 * U_N + off] = h2;
            }
}

// ============ scores = U @ {q,k,k}^T : planes -> out slots 1..3 ===============
__global__ __launch_bounds__(256) void k_scores(const u16* __restrict__ qP,
                                                const u16* __restrict__ kP,
                                                const u16* __restrict__ UP,
                                                float* __restrict__ out) {
    int z = blockIdx.z, b = z / 3, m = z % 3;
    const u16* A  = UP + (size_t)z * ((size_t)L_ * D_);
    const u16* Bp = ((m == 0) ? qP : kP) + (size_t)b * L_ * D_;
    int m0 = blockIdx.y * 64, n0 = blockIdx.x * 64;
    double ov[2][2][4];
    gemm_core<false, false>(A, U_N, D_, Bp, QK_N, D_, D_, m0, n0, threadIdx.x, ov);
    float* Co = out + (size_t)(1 + m) * SLOT + (size_t)b * LL;
    int lane = threadIdx.x & 63, w = threadIdx.x >> 6;
    int wm = (w & 1) << 5, wn = (w >> 1) << 5;
    int col = lane & 15, rbase = (lane >> 4) << 2;
#pragma unroll
    for (int fi = 0; fi < 2; ++fi)
#pragma unroll
        for (int fj = 0; fj < 2; ++fj)
#pragma unroll
            for (int r = 0; r < 4; ++r) {
                int mm = m0 + wm + fi * 16 + rbase + r;
                int nn = n0 + wn + fj * 16 + col;
                Co[(size_t)mm * L_ + nn] = (float)ov[fi][fj][r];
            }
}

// ============ entmax-1.5: 12 bisection + 5 safeguarded Newton (fp64) ==========
__global__ __launch_bounds__(256) void k_entmax(float* __restrict__ base, int nrows,
                                                const float* __restrict__ wC,
                                                const float* __restrict__ wF,
                                                const float* __restrict__ wS,
                                                int clip) {
    int tid = threadIdx.x;
    int lane = tid & 63;
    int r = blockIdx.x * 4 + (tid >> 6);
    if (r >= nrows) return;
    double w = 1.0;
    if (wC) {
        int m = r >> 12;                 // 4096 rows per matrix
        const float* wp = (m == 0) ? wC : (m == 1) ? wF : wS;
        w = 2.0 / (1.0 + exp(-(double)wp[0]));
    }
    float* row = base + (size_t)r * L_;
    double z[32];
    double mx = -1.0e300;
#pragma unroll
    for (int j = 0; j < 32; ++j) {
        z[j] = 0.5 * w * (double)row[lane + (j << 6)];
        mx = fmax(mx, z[j]);
    }
    for (int off = 32; off; off >>= 1) mx = fmax(mx, __shfl_xor(mx, off));
#pragma unroll
    for (int j = 0; j < 32; ++j) z[j] -= mx;
    double lo = -1.0, hi = 0.0;
    for (int it = 0; it < 12; ++it) {
        double tau = 0.5 * (lo + hi);
        double ssum = 0.0;
#pragma unroll
        for (int j = 0; j < 32; ++j) {
            double t = fmax(z[j] - tau, 0.0);
            ssum = fma(t, t, ssum);
        }
        for (int off = 32; off; off >>= 1) ssum += __shfl_xor(ssum, off);
        if (ssum >= 1.0) lo = tau; else hi = tau;
    }
    double tau = lo;   // g(lo) >= 1 invariant; Newton on convex f stays left of root
    for (int it = 0; it < 5; ++it) {
        double s1 = 0.0, s2 = 0.0;
#pragma unroll
        for (int j = 0; j < 32; ++j) {
            double t = fmax(z[j] - tau, 0.0);
            s1 += t;
            s2 = fma(t, t, s2);
        }
        for (int off = 32; off; off >>= 1) { s1 += __shfl_xor(s1, off); s2 += __shfl_xor(s2, off); }
        double denom = 2.0 * s1;
        if (denom > 1e-300) tau += fmax((s2 - 1.0) / denom, 0.0);
    }
#pragma unroll
    for (int j = 0; j < 32; ++j) {
        double t = fmax(z[j] - tau, 0.0);
        double p = t * t;
        if (clip) p = fmin(p, 1.0 - 1e-6);
        row[lane + (j << 6)] = (float)p;
    }
}

// ============ column sums (deterministic, fp64) ===============================
__global__ __launch_bounds__(256) void k_colsum(const float* __restrict__ out,
                                                double* __restrict__ csC,
                                                double* __restrict__ csS) {
    int which = blockIdx.z >> 1, b = blockIdx.z & 1;
    const float* mat = out + (size_t)(which ? 3 : 1) * SLOT + (size_t)b * LL;
    int j = blockIdx.x * 256 + threadIdx.x;
    double s = 0.0;
#pragma unroll 8
    for (int r = 0; r < L_; ++r) s += (double)mat[(size_t)r * L_ + j];
    (which ? csS : csC)[b * L_ + j] = s;
}

// ============ finalize p's, build H (fp64) ====================================
__global__ __launch_bounds__(256) void k_finalize(float* __restrict__ out,
                                                  const double* __restrict__ csC,
                                                  const double* __restrict__ csS) {
    int row = blockIdx.x;               // b*2048 + i
    int i = row & (L_ - 1), b = row >> 11;
    size_t ro = (size_t)row * L_;
    float* H  = out + ro;
    float* pC = out + SLOT + ro;
    float* pF = out + 2 * SLOT + ro;
    float* pS = out + 3 * SLOT + ro;
    const double* cc = csC + b * L_;
    const double* cs = csS + b * L_;
    const double A1 = 1.0 - 2e-6;
    for (int j = threadIdx.x; j < L_; j += 256) {
        double c = (double)pC[j] * rsqrt(cc[j] + 1e-6);
        double f = (double)pF[j];
        double s = (double)pS[j] * rsqrt(cs[j] + 1e-6);
        c = fmax(A1 * c + 1e-6, 1e-6);
        f = fmax(A1 * f + 1e-6, 1e-6);
        s = fmax(A1 * s + 1e-6, 1e-6);
        pC[j] = (float)c; pF[j] = (float)f; pS[j] = (float)s;
        H[j] = (j == i) ? -1e9f : (float)((log(c) + log(f) + log(s)) * (1.0 / 3.0));
    }
}

// ============ launch ==========================================================
extern "C" void kernel_launch(void* const* d_in, const int* in_sizes, int n_in,
                              void* d_out, int out_size, void* d_ws, size_t ws_size,
                              hipStream_t stream) {
    const float* x  = (const float*)d_in[0];
    const float* Wq = (const float*)d_in[1];
    const float* Wk = (const float*)d_in[2];
    const float* qg = (const float*)d_in[3];
    const float* qb = (const float*)d_in[4];
    const float* kg = (const float*)d_in[5];
    const float* kb = (const float*)d_in[6];
    const float* wC = (const float*)d_in[7];
    const float* wF = (const float*)d_in[8];
    const float* wS = (const float*)d_in[9];
    float* out = (float*)d_out;

    // workspace: [ UP 3*U_N u16 | qP | kP | GP | trig | csC | csS ]  (~81 MB)
    // qraw/kraw alias UP's first 16.8 MB (dead before k_u writes UP).
    char* wsb = (char*)d_ws;
    u16*    UP   = (u16*)wsb;
    float*  qraw = (float*)wsb;
    float*  kraw = qraw + QK_N;
    wsb += 3 * U_N * sizeof(u16);                          // 37.75 MB
    u16*    qP   = (u16*)wsb;  wsb += 3 * QK_N * sizeof(u16);   // 12.6 MB
    u16*    kP   = (u16*)wsb;  wsb += 3 * QK_N * sizeof(u16);   // 12.6 MB
    u16*    GP   = (u16*)wsb;  wsb += 3 * G_N * sizeof(u16);    // 9.4 MB
    double* tg   = (double*)wsb; wsb += (size_t)L_ * 512 * sizeof(double); // 8.4 MB
    double* csC  = (double*)wsb; wsb += (size_t)B_ * L_ * sizeof(double);
    double* csS  = (double*)wsb;

    k_trig    <<<dim3(L_),        256, 0, stream>>>(tg);
    k_proj    <<<dim3(8, 64, 2),  256, 0, stream>>>(x, Wq, Wk, qraw, kraw);
    k_lnrope  <<<dim3(B_ * L_),   128, 0, stream>>>(qraw, kraw, tg, qg, qb, kg, kb, qP, kP);
    k_gram    <<<dim3(8, 8, 6),   256, 0, stream>>>(qP, kP, GP);
    k_u       <<<dim3(8, 32, 6),  256, 0, stream>>>(qP, kP, GP, UP);
    k_scores  <<<dim3(32, 32, 6), 256, 0, stream>>>(qP, kP, UP, out);
    k_entmax  <<<dim3(3072),      256, 0, stream>>>(out + SLOT, 3 * B_ * L_, wC, wF, wS, 1);
    k_colsum  <<<dim3(8, 1, 4),   256, 0, stream>>>(out, csC, csS);
    k_finalize<<<dim3(B_ * L_),   256, 0, stream>>>(out, csC, csS);
    k_entmax  <<<dim3(1024),      256, 0, stream>>>(out, B_ * L_, nullptr, nullptr, nullptr, 0);
}

// Round 7
// 1005.175 us; speedup vs baseline: 1.7025x; 1.0354x over previous
//
#include <hip/hip_runtime.h>
#include <cstddef>
#include <math.h>

// ---------------- problem constants ----------------
#define B_   2
#define L_   2048
#define D_   512
#define E_   768
static const size_t LL   = (size_t)L_ * L_;
static const size_t SLOT = (size_t)B_ * LL;

#define QK_N  ((size_t)B_ * L_ * D_)       // 2097152
#define G1_N  ((size_t)512 * 512)          // 262144
#define G_N   ((size_t)6 * G1_N)           // 1572864
#define U_N   ((size_t)6 * L_ * D_)        // 6291456

typedef unsigned short u16;
typedef __attribute__((ext_vector_type(8))) short short8;   // 8 bf16
typedef __attribute__((ext_vector_type(4))) float f32x4;

// ---------------- bf16x3 exact split of fp32 ---------------------------------
__device__ __forceinline__ u16 f2bf(float f) {
    unsigned x = __float_as_uint(f);
    unsigned r = (x + 0x7fffu + ((x >> 16) & 1u)) >> 16;    // RNE
    return (u16)r;
}
__device__ __forceinline__ float bf2f(u16 h) { return __uint_as_float(((unsigned)h) << 16); }
__device__ __forceinline__ void split3(float f, u16& h0, u16& h1, u16& h2) {
    h0 = f2bf(f); float r = f - bf2f(h0);
    h1 = f2bf(r); r -= bf2f(h1);
    h2 = f2bf(r);                                            // exact: fp32 = h0+h1+h2
}

#define BKP 40   // LDS row pitch in u16

// ============ plane-based stagers =============================================
__device__ __forceinline__ void pstage_MK(const u16* __restrict__ P, size_t pstride, int ld,
                                          int r0, int k0, int tid, u16 S[3][64][BKP]) {
    int m = tid >> 2, kq = (tid & 3) << 3;
#pragma unroll
    for (int s = 0; s < 3; ++s) {
        const u16* src = P + (size_t)s * pstride + (size_t)(r0 + m) * ld + k0 + kq;
        ushort4 v0 = *reinterpret_cast<const ushort4*>(src);
        ushort4 v1 = *reinterpret_cast<const ushort4*>(src + 4);
        *reinterpret_cast<ushort4*>(&S[s][m][kq]) = v0;
        *reinterpret_cast<ushort4*>(&S[s][m][kq + 4]) = v1;
    }
}
__device__ __forceinline__ void pstage_KM(const u16* __restrict__ P, size_t pstride, int ld,
                                          int r0, int k0, int tid, u16 S[3][64][BKP]) {
    int k = tid >> 3, mq = (tid & 7) << 3;
#pragma unroll
    for (int s = 0; s < 3; ++s) {
        const u16* src = P + (size_t)s * pstride + (size_t)(k0 + k) * ld + r0 + mq;
        ushort4 v0 = *reinterpret_cast<const ushort4*>(src);
        ushort4 v1 = *reinterpret_cast<const ushort4*>(src + 4);
        S[s][mq + 0][k] = v0.x; S[s][mq + 1][k] = v0.y; S[s][mq + 2][k] = v0.z; S[s][mq + 3][k] = v0.w;
        S[s][mq + 4][k] = v1.x; S[s][mq + 5][k] = v1.y; S[s][mq + 6][k] = v1.z; S[s][mq + 7][k] = v1.w;
    }
}

// ============ 6-tier bf16x3 MFMA core (64x64 tile, BK=32) =====================
// tiers: H=a0b0; M=a0b1+a1b0 (2^-8); L=a0b2+a1b1+a2b0 (2^-16). Dropped 2^-26.
// H promoted to fp64 every 2 K-steps (K=64 chunks — round-4-proven numerics).
template<bool AKM, bool BKM>
__device__ __forceinline__ void gemm_core(const u16* __restrict__ Ap, size_t Aps, int lda,
                                          const u16* __restrict__ Bp, size_t Bps, int ldb,
                                          int K, int m0, int n0, int tid,
                                          double outv[2][2][4]) {
    __shared__ u16 SA[3][64][BKP], SB[3][64][BKP];
    f32x4 accH[2][2], accM[2][2], accL[2][2];
#pragma unroll
    for (int i = 0; i < 2; ++i)
#pragma unroll
        for (int j = 0; j < 2; ++j) {
            accH[i][j] = (f32x4){0.f, 0.f, 0.f, 0.f};
            accM[i][j] = (f32x4){0.f, 0.f, 0.f, 0.f};
            accL[i][j] = (f32x4){0.f, 0.f, 0.f, 0.f};
        }
    double accD[2][2][4] = {};
    int lane = tid & 63, w = tid >> 6;
    int wm = (w & 1) << 5, wn = (w >> 1) << 5;
    int fr = lane & 15, ko = (lane >> 4) << 3;

    int nstep = K >> 5;
    for (int s = 0; s < nstep; ++s) {
        int k0 = s << 5;
        if (AKM) pstage_KM(Ap, Aps, lda, m0, k0, tid, SA); else pstage_MK(Ap, Aps, lda, m0, k0, tid, SA);
        if (BKM) pstage_KM(Bp, Bps, ldb, n0, k0, tid, SB); else pstage_MK(Bp, Bps, ldb, n0, k0, tid, SB);
        __syncthreads();
        short8 a[2][3], b[2][3];
#pragma unroll
        for (int f = 0; f < 2; ++f)
#pragma unroll
            for (int sp = 0; sp < 3; ++sp) {
                a[f][sp] = *reinterpret_cast<const short8*>(&SA[sp][wm + f * 16 + fr][ko]);
                b[f][sp] = *reinterpret_cast<const short8*>(&SB[sp][wn + f * 16 + fr][ko]);
            }
#pragma unroll
        for (int fi = 0; fi < 2; ++fi)
#pragma unroll
            for (int fj = 0; fj < 2; ++fj) {
                accH[fi][fj] = __builtin_amdgcn_mfma_f32_16x16x32_bf16(a[fi][0], b[fj][0], accH[fi][fj], 0, 0, 0);
                accM[fi][fj] = __builtin_amdgcn_mfma_f32_16x16x32_bf16(a[fi][0], b[fj][1], accM[fi][fj], 0, 0, 0);
                accM[fi][fj] = __builtin_amdgcn_mfma_f32_16x16x32_bf16(a[fi][1], b[fj][0], accM[fi][fj], 0, 0, 0);
                accL[fi][fj] = __builtin_amdgcn_mfma_f32_16x16x32_bf16(a[fi][0], b[fj][2], accL[fi][fj], 0, 0, 0);
                accL[fi][fj] = __builtin_amdgcn_mfma_f32_16x16x32_bf16(a[fi][1], b[fj][1], accL[fi][fj], 0, 0, 0);
                accL[fi][fj] = __builtin_amdgcn_mfma_f32_16x16x32_bf16(a[fi][2], b[fj][0], accL[fi][fj], 0, 0, 0);
            }
        __syncthreads();
        if (s & 1) {
#pragma unroll
            for (int fi = 0; fi < 2; ++fi)
#pragma unroll
                for (int fj = 0; fj < 2; ++fj) {
#pragma unroll
                    for (int r = 0; r < 4; ++r) accD[fi][fj][r] += (double)accH[fi][fj][r];
                    accH[fi][fj] = (f32x4){0.f, 0.f, 0.f, 0.f};
                }
        }
    }
#pragma unroll
    for (int fi = 0; fi < 2; ++fi)
#pragma unroll
        for (int fj = 0; fj < 2; ++fj)
#pragma unroll
            for (int r = 0; r < 4; ++r)
                outv[fi][fj][r] = accD[fi][fj][r] + (double)accH[fi][fj][r]
                                + (double)accM[fi][fj][r] + (double)accL[fi][fj][r];
}

// ============ k_proj: fp32 sources, split3 staging, 6-tier ====================
__device__ __forceinline__ void stage_MKf(const float* __restrict__ P, int ld,
                                          int r0, int k0, int tid, u16 S[3][64][BKP]) {
#pragma unroll
    for (int i = 0; i < 2; ++i) {
        int f = tid + i * 256;
        int m = f >> 3, kq = (f & 7) << 2;
        float4 v = *reinterpret_cast<const float4*>(P + (size_t)(r0 + m) * ld + k0 + kq);
        float vv[4] = {v.x, v.y, v.z, v.w};
        u16 h[3][4];
#pragma unroll
        for (int c = 0; c < 4; ++c) split3(vv[c], h[0][c], h[1][c], h[2][c]);
#pragma unroll
        for (int s = 0; s < 3; ++s)
            *reinterpret_cast<ushort4*>(&S[s][m][kq]) = make_ushort4(h[s][0], h[s][1], h[s][2], h[s][3]);
    }
}

__global__ __launch_bounds__(256) void k_proj(const float* __restrict__ x,
                                              const float* __restrict__ Wq,
                                              const float* __restrict__ Wk,
                                              float* __restrict__ qraw,
                                              float* __restrict__ kraw) {
    __shared__ u16 SA[3][64][BKP], SB[3][64][BKP];
    const float* W = blockIdx.z ? Wk : Wq;
    float* out = blockIdx.z ? kraw : qraw;
    int tid = threadIdx.x;
    int m0 = blockIdx.y * 64, n0 = blockIdx.x * 64;
    f32x4 accH[2][2], accM[2][2], accL[2][2];
#pragma unroll
    for (int i = 0; i < 2; ++i)
#pragma unroll
        for (int j = 0; j < 2; ++j) {
            accH[i][j] = (f32x4){0.f, 0.f, 0.f, 0.f};
            accM[i][j] = (f32x4){0.f, 0.f, 0.f, 0.f};
            accL[i][j] = (f32x4){0.f, 0.f, 0.f, 0.f};
        }
    double accD[2][2][4] = {};
    int lane = tid & 63, w = tid >> 6;
    int wm = (w & 1) << 5, wn = (w >> 1) << 5;
    int fr = lane & 15, ko = (lane >> 4) << 3;
    for (int s = 0; s < (E_ >> 5); ++s) {
        int k0 = s << 5;
        stage_MKf(x, E_, m0, k0, tid, SA);
        stage_MKf(W, E_, n0, k0, tid, SB);
        __syncthreads();
        short8 a[2][3], b[2][3];
#pragma unroll
        for (int f = 0; f < 2; ++f)
#pragma unroll
            for (int sp = 0; sp < 3; ++sp) {
                a[f][sp] = *reinterpret_cast<const short8*>(&SA[sp][wm + f * 16 + fr][ko]);
                b[f][sp] = *reinterpret_cast<const short8*>(&SB[sp][wn + f * 16 + fr][ko]);
            }
#pragma unroll
        for (int fi = 0; fi < 2; ++fi)
#pragma unroll
            for (int fj = 0; fj < 2; ++fj) {
                accH[fi][fj] = __builtin_amdgcn_mfma_f32_16x16x32_bf16(a[fi][0], b[fj][0], accH[fi][fj], 0, 0, 0);
                accM[fi][fj] = __builtin_amdgcn_mfma_f32_16x16x32_bf16(a[fi][0], b[fj][1], accM[fi][fj], 0, 0, 0);
                accM[fi][fj] = __builtin_amdgcn_mfma_f32_16x16x32_bf16(a[fi][1], b[fj][0], accM[fi][fj], 0, 0, 0);
                accL[fi][fj] = __builtin_amdgcn_mfma_f32_16x16x32_bf16(a[fi][0], b[fj][2], accL[fi][fj], 0, 0, 0);
                accL[fi][fj] = __builtin_amdgcn_mfma_f32_16x16x32_bf16(a[fi][1], b[fj][1], accL[fi][fj], 0, 0, 0);
                accL[fi][fj] = __builtin_amdgcn_mfma_f32_16x16x32_bf16(a[fi][2], b[fj][0], accL[fi][fj], 0, 0, 0);
            }
        __syncthreads();
        if (s & 1) {
#pragma unroll
            for (int fi = 0; fi < 2; ++fi)
#pragma unroll
                for (int fj = 0; fj < 2; ++fj) {
#pragma unroll
                    for (int r = 0; r < 4; ++r) accD[fi][fj][r] += (double)accH[fi][fj][r];
                    accH[fi][fj] = (f32x4){0.f, 0.f, 0.f, 0.f};
                }
        }
    }
    int col = lane & 15, rbase = (lane >> 4) << 2;
#pragma unroll
    for (int fi = 0; fi < 2; ++fi)
#pragma unroll
        for (int fj = 0; fj < 2; ++fj)
#pragma unroll
            for (int r = 0; r < 4; ++r) {
                double v = accD[fi][fj][r] + (double)accH[fi][fj][r]
                         + (double)accM[fi][fj][r] + (double)accL[fi][fj][r];
                int mm = m0 + wm + fi * 16 + rbase + r;
                int nn = n0 + wn + fj * 16 + col;
                out[(size_t)mm * D_ + nn] = (float)v;
            }
}

// ============ RoPE table (fp64, once per launch) ==============================
__global__ __launch_bounds__(256) void k_trig(double* __restrict__ tg) {
    int l = blockIdx.x, j = threadIdx.x;
    double e = (double)j * (1.0 / 256.0);
    double inv = pow(10000.0, -e);
    double ang = (double)l * inv;
    tg[(size_t)l * 512 + j] = cos(ang);
    tg[(size_t)l * 512 + 256 + j] = sin(ang);
}

// ============ LayerNorm + RoPE (fp64) -> bf16x3 planes ========================
__global__ __launch_bounds__(128) void k_lnrope(const float* __restrict__ qraw,
                                                const float* __restrict__ kraw,
                                                const double* __restrict__ tg,
                                                const float* __restrict__ qg, const float* __restrict__ qb,
                                                const float* __restrict__ kg, const float* __restrict__ kb,
                                                u16* __restrict__ qP, u16* __restrict__ kP) {
    int row = blockIdx.x;           // b*2048 + l
    int l = row & (L_ - 1);
    int tid = threadIdx.x;
    __shared__ double nrow[D_];
    __shared__ double red[4];
    __shared__ double cs_[256], sn_[256];
    for (int j = tid; j < 256; j += 128) {
        cs_[j] = tg[(size_t)l * 512 + j];
        sn_[j] = tg[(size_t)l * 512 + 256 + j];
    }
    __syncthreads();
    for (int pass = 0; pass < 2; ++pass) {
        const float* rp = (pass ? kraw : qraw) + (size_t)row * D_;
        const float* g  = pass ? kg : qg;
        const float* bt = pass ? kb : qb;
        u16* P = pass ? kP : qP;
        float4 v = reinterpret_cast<const float4*>(rp)[tid];
        double vv[4] = {(double)v.x, (double)v.y, (double)v.z, (double)v.w};
        double s = vv[0] + vv[1] + vv[2] + vv[3];
        double s2 = vv[0]*vv[0] + vv[1]*vv[1] + vv[2]*vv[2] + vv[3]*vv[3];
        for (int off = 32; off; off >>= 1) { s += __shfl_xor(s, off); s2 += __shfl_xor(s2, off); }
        int wv = tid >> 6;
        if ((tid & 63) == 0) { red[wv * 2] = s; red[wv * 2 + 1] = s2; }
        __syncthreads();
        double mu  = (red[0] + red[2]) * (1.0 / D_);
        double var = (red[1] + red[3]) * (1.0 / D_) - mu * mu;
        double rs = rsqrt(var + 1e-5);
        int d0 = tid * 4;
        double o[4];
#pragma unroll
        for (int c = 0; c < 4; ++c) {
            int d = d0 + c;
            o[c] = (vv[c] - mu) * rs * (double)g[d] + (double)bt[d];
        }
        __syncthreads();
#pragma unroll
        for (int c = 0; c < 4; ++c) nrow[d0 + c] = o[c];
        __syncthreads();
        u16 h[3][4];
#pragma unroll
        for (int c = 0; c < 4; ++c) {
            int d = d0 + c;
            double rot = (d < 256) ? -nrow[d + 256] : nrow[d - 256];
            float ov = (float)(nrow[d] * cs_[d & 255] + rot * sn_[d & 255]);
            split3(ov, h[0][c], h[1][c], h[2][c]);
        }
        size_t off = (size_t)row * D_ + d0;
#pragma unroll
        for (int sp = 0; sp < 3; ++sp)
            *reinterpret_cast<ushort4*>(P + sp * QK_N + off) = make_ushort4(h[sp][0], h[sp][1], h[sp][2], h[sp][3]);
        __syncthreads();
    }
}

// ============ Gram split-K=2: planes -> fp32 partials =========================
// blockIdx.z = z*2 + half; z = b*3+m
__global__ __launch_bounds__(256) void k_gram(const u16* __restrict__ qP,
                                              const u16* __restrict__ kP,
                                              float* __restrict__ Gpart) {
    int zz = blockIdx.z, half = zz & 1, z = zz >> 1;
    int b = z / 3, m = z % 3;
    const u16* A  = ((m == 2) ? qP : kP) + (size_t)b * L_ * D_ + (size_t)half * (L_ / 2) * D_;
    const u16* Bp = ((m == 0) ? kP : qP) + (size_t)b * L_ * D_ + (size_t)half * (L_ / 2) * D_;
    int m0 = blockIdx.y * 64, n0 = blockIdx.x * 64;
    double ov[2][2][4];
    gemm_core<true, true>(A, QK_N, D_, Bp, QK_N, D_, L_ / 2, m0, n0, threadIdx.x, ov);
    float* Gg = Gpart + (size_t)half * G_N + (size_t)z * G1_N;
    int lane = threadIdx.x & 63, w = threadIdx.x >> 6;
    int wm = (w & 1) << 5, wn = (w >> 1) << 5;
    int col = lane & 15, rbase = (lane >> 4) << 2;
#pragma unroll
    for (int fi = 0; fi < 2; ++fi)
#pragma unroll
        for (int fj = 0; fj < 2; ++fj)
#pragma unroll
            for (int r = 0; r < 4; ++r) {
                int mm = m0 + wm + fi * 16 + rbase + r;
                int nn = n0 + wn + fj * 16 + col;
                Gg[(size_t)mm * 512 + nn] = (float)ov[fi][fj][r];
            }
}

// ============ sum partials + split into G planes ==============================
__global__ __launch_bounds__(256) void k_gsplit(const float* __restrict__ Gpart,
                                                u16* __restrict__ GP) {
    size_t i = (size_t)blockIdx.x * 256 + threadIdx.x;   // over G_N
    float g = Gpart[i] + Gpart[G_N + i];
    u16 h0, h1, h2; split3(g, h0, h1, h2);
    GP[i] = h0; GP[G_N + i] = h1; GP[2 * G_N + i] = h2;
}

// ============ U = {q,q,k} @ G : planes -> U planes ============================
__global__ __launch_bounds__(256) void k_u(const u16* __restrict__ qP,
                                           const u16* __restrict__ kP,
                                           const u16* __restrict__ GP,
                                           u16* __restrict__ UP) {
    int z = blockIdx.z, b = z / 3, m = z % 3;
    const u16* A  = ((m == 2) ? kP : qP) + (size_t)b * L_ * D_;
    const u16* Bp = GP + (size_t)z * G1_N;
    int m0 = blockIdx.y * 64, n0 = blockIdx.x * 64;
    double ov[2][2][4];
    gemm_core<false, true>(A, QK_N, D_, Bp, G_N, 512, D_, m0, n0, threadIdx.x, ov);
    int lane = threadIdx.x & 63, w = threadIdx.x >> 6;
    int wm = (w & 1) << 5, wn = (w >> 1) << 5;
    int col = lane & 15, rbase = (lane >> 4) << 2;
#pragma unroll
    for (int fi = 0; fi < 2; ++fi)
#pragma unroll
        for (int fj = 0; fj < 2; ++fj)
#pragma unroll
            for (int r = 0; r < 4; ++r) {
                float uf = (float)ov[fi][fj][r];
                int mm = m0 + wm + fi * 16 + rbase + r;
                int nn = n0 + wn + fj * 16 + col;
                size_t off = (size_t)z * ((size_t)L_ * D_) + (size_t)mm * D_ + nn;
                u16 h0, h1, h2; split3(uf, h0, h1, h2);
                UP[off] = h0; UP[U_N + off] = h1; UP[2 * U_N + off] = h2;
            }
}

// ============ scores = U @ {q,k,k}^T : planes -> out slots 1..3 ===============
__global__ __launch_bounds__(256) void k_scores(const u16* __restrict__ qP,
                                                const u16* __restrict__ kP,
                                                const u16* __restrict__ UP,
                                                float* __restrict__ out) {
    int z = blockIdx.z, b = z / 3, m = z % 3;
    const u16* A  = UP + (size_t)z * ((size_t)L_ * D_);
    const u16* Bp = ((m == 0) ? qP : kP) + (size_t)b * L_ * D_;
    int m0 = blockIdx.y * 64, n0 = blockIdx.x * 64;
    double ov[2][2][4];
    gemm_core<false, false>(A, U_N, D_, Bp, QK_N, D_, D_, m0, n0, threadIdx.x, ov);
    float* Co = out + (size_t)(1 + m) * SLOT + (size_t)b * LL;
    int lane = threadIdx.x & 63, w = threadIdx.x >> 6;
    int wm = (w & 1) << 5, wn = (w >> 1) << 5;
    int col = lane & 15, rbase = (lane >> 4) << 2;
#pragma unroll
    for (int fi = 0; fi < 2; ++fi)
#pragma unroll
        for (int fj = 0; fj < 2; ++fj)
#pragma unroll
            for (int r = 0; r < 4; ++r) {
                int mm = m0 + wm + fi * 16 + rbase + r;
                int nn = n0 + wn + fj * 16 + col;
                Co[(size_t)mm * L_ + nn] = (float)ov[fi][fj][r];
            }
}

// ============ entmax-1.5: 12 bisection + 5 safeguarded Newton (fp64) ==========
__global__ __launch_bounds__(256) void k_entmax(float* __restrict__ base, int nrows,
                                                const float* __restrict__ wC,
                                                const float* __restrict__ wF,
                                                const float* __restrict__ wS,
                                                int clip) {
    int tid = threadIdx.x;
    int lane = tid & 63;
    int r = blockIdx.x * 4 + (tid >> 6);
    if (r >= nrows) return;
    double w = 1.0;
    if (wC) {
        int m = r >> 12;                 // 4096 rows per matrix
        const float* wp = (m == 0) ? wC : (m == 1) ? wF : wS;
        w = 2.0 / (1.0 + exp(-(double)wp[0]));
    }
    float* row = base + (size_t)r * L_;
    double z[32];
    double mx = -1.0e300;
#pragma unroll
    for (int j = 0; j < 32; ++j) {
        z[j] = 0.5 * w * (double)row[lane + (j << 6)];
        mx = fmax(mx, z[j]);
    }
    for (int off = 32; off; off >>= 1) mx = fmax(mx, __shfl_xor(mx, off));
#pragma unroll
    for (int j = 0; j < 32; ++j) z[j] -= mx;
    double lo = -1.0, hi = 0.0;
    for (int it = 0; it < 12; ++it) {
        double tau = 0.5 * (lo + hi);
        double ssum = 0.0;
#pragma unroll
        for (int j = 0; j < 32; ++j) {
            double t = fmax(z[j] - tau, 0.0);
            ssum = fma(t, t, ssum);
        }
        for (int off = 32; off; off >>= 1) ssum += __shfl_xor(ssum, off);
        if (ssum >= 1.0) lo = tau; else hi = tau;
    }
    double tau = lo;   // g(lo) >= 1 invariant; Newton on convex f stays left of root
    for (int it = 0; it < 5; ++it) {
        double s1 = 0.0, s2 = 0.0;
#pragma unroll
        for (int j = 0; j < 32; ++j) {
            double t = fmax(z[j] - tau, 0.0);
            s1 += t;
            s2 = fma(t, t, s2);
        }
        for (int off = 32; off; off >>= 1) { s1 += __shfl_xor(s1, off); s2 += __shfl_xor(s2, off); }
        double denom = 2.0 * s1;
        if (denom > 1e-300) tau += fmax((s2 - 1.0) / denom, 0.0);
    }
#pragma unroll
    for (int j = 0; j < 32; ++j) {
        double t = fmax(z[j] - tau, 0.0);
        double p = t * t;
        if (clip) p = fmin(p, 1.0 - 1e-6);
        row[lane + (j << 6)] = (float)p;
    }
}

// ============ column sums: partials (deterministic, parallel) =================
// grid (8,16,4): bz = which*2+b, by = 128-row chunk, bx*256+tid = column j
__global__ __launch_bounds__(256) void k_colsum(const float* __restrict__ out,
                                                double* __restrict__ part) {
    int bz = blockIdx.z, which = bz >> 1, b = bz & 1;
    const float* mat = out + (size_t)(which ? 3 : 1) * SLOT + (size_t)b * LL;
    int j = blockIdx.x * 256 + threadIdx.x;
    int r0 = blockIdx.y * 128;
    double s = 0.0;
#pragma unroll 8
    for (int r = 0; r < 128; ++r) s += (double)mat[(size_t)(r0 + r) * L_ + j];
    part[((size_t)bz * 16 + blockIdx.y) * L_ + j] = s;
}

// grid (32): reduce 16 chunks -> csC/csS
__global__ __launch_bounds__(256) void k_colred(const double* __restrict__ part,
                                                double* __restrict__ csC,
                                                double* __restrict__ csS) {
    int g = blockIdx.x * 256 + threadIdx.x;   // 0..8191 = bz*2048 + j
    int bz = g >> 11, j = g & (L_ - 1);
    int which = bz >> 1, b = bz & 1;
    double s = 0.0;
#pragma unroll
    for (int c = 0; c < 16; ++c) s += part[((size_t)bz * 16 + c) * L_ + j];
    (which ? csS : csC)[b * L_ + j] = s;
}

// ============ finalize p's, build H (fp64) ====================================
__global__ __launch_bounds__(256) void k_finalize(float* __restrict__ out,
                                                  const double* __restrict__ csC,
                                                  const double* __restrict__ csS) {
    int row = blockIdx.x;               // b*2048 + i
    int i = row & (L_ - 1), b = row >> 11;
    size_t ro = (size_t)row * L_;
    float* H  = out + ro;
    float* pC = out + SLOT + ro;
    float* pF = out + 2 * SLOT + ro;
    float* pS = out + 3 * SLOT + ro;
    const double* cc = csC + b * L_;
    const double* cs = csS + b * L_;
    const double A1 = 1.0 - 2e-6;
    for (int j = threadIdx.x; j < L_; j += 256) {
        double c = (double)pC[j] * rsqrt(cc[j] + 1e-6);
        double f = (double)pF[j];
        double s = (double)pS[j] * rsqrt(cs[j] + 1e-6);
        c = fmax(A1 * c + 1e-6, 1e-6);
        f = fmax(A1 * f + 1e-6, 1e-6);
        s = fmax(A1 * s + 1e-6, 1e-6);
        pC[j] = (float)c; pF[j] = (float)f; pS[j] = (float)s;
        H[j] = (j == i) ? -1e9f : (float)((log(c) + log(f) + log(s)) * (1.0 / 3.0));
    }
}

// ============ launch ==========================================================
extern "C" void kernel_launch(void* const* d_in, const int* in_sizes, int n_in,
                              void* d_out, int out_size, void* d_ws, size_t ws_size,
                              hipStream_t stream) {
    const float* x  = (const float*)d_in[0];
    const float* Wq = (const float*)d_in[1];
    const float* Wk = (const float*)d_in[2];
    const float* qg = (const float*)d_in[3];
    const float* qb = (const float*)d_in[4];
    const float* kg = (const float*)d_in[5];
    const float* kb = (const float*)d_in[6];
    const float* wC = (const float*)d_in[7];
    const float* wF = (const float*)d_in[8];
    const float* wS = (const float*)d_in[9];
    float* out = (float*)d_out;

    // workspace (80.74 MB total — matches round-5's proven footprint).
    // Liveness-based overlays:
    //   qraw/kraw : UP bytes [0, 16.78 MB)   — dead after k_lnrope, before k_u
    //   Gpart     : UP bytes [16.78, 29.36 MB) — written k_gram, dead after
    //               k_gsplit, before k_u overwrites UP
    //   part/csC/csS : inside tg region — tg dead after k_lnrope
    char* wsb = (char*)d_ws;
    u16*    UP   = (u16*)wsb;
    float*  qraw = (float*)wsb;
    float*  kraw = qraw + QK_N;
    float*  Gpart = (float*)(wsb + 2 * QK_N * sizeof(float));   // after qraw+kraw
    wsb += 3 * U_N * sizeof(u16);                               // 37.75 MB
    u16*    qP    = (u16*)wsb;   wsb += 3 * QK_N * sizeof(u16); // 12.6 MB
    u16*    kP    = (u16*)wsb;   wsb += 3 * QK_N * sizeof(u16); // 12.6 MB
    u16*    GP    = (u16*)wsb;   wsb += 3 * G_N * sizeof(u16);  // 9.4 MB
    double* tg    = (double*)wsb;                                // 8.4 MB region
    double* part  = tg;                                          // 1 MB   (alias)
    double* csC   = tg + (size_t)4 * 16 * L_;                    // 32 KB  (alias)
    double* csS   = csC + (size_t)B_ * L_;                       // 32 KB  (alias)

    k_trig    <<<dim3(L_),        256, 0, stream>>>(tg);
    k_proj    <<<dim3(8, 64, 2),  256, 0, stream>>>(x, Wq, Wk, qraw, kraw);
    k_lnrope  <<<dim3(B_ * L_),   128, 0, stream>>>(qraw, kraw, tg, qg, qb, kg, kb, qP, kP);
    k_gram    <<<dim3(8, 8, 12),  256, 0, stream>>>(qP, kP, Gpart);
    k_gsplit  <<<dim3(G_N / 256), 256, 0, stream>>>(Gpart, GP);
    k_u       <<<dim3(8, 32, 6),  256, 0, stream>>>(qP, kP, GP, UP);
    k_scores  <<<dim3(32, 32, 6), 256, 0, stream>>>(qP, kP, UP, out);
    k_entmax  <<<dim3(3072),      256, 0, stream>>>(out + SLOT, 3 * B_ * L_, wC, wF, wS, 1);
    k_colsum  <<<dim3(8, 16, 4),  256, 0, stream>>>(out, part);
    k_colred  <<<dim3(32),        256, 0, stream>>>(part, csC, csS);
    k_finalize<<<dim3(B_ * L_),   256, 0, stream>>>(out, csC, csS);
    k_entmax  <<<dim3(1024),      256, 0, stream>>>(out, B_ * L_, nullptr, nullptr, nullptr, 0);
}

// Round 8
// 791.765 us; speedup vs baseline: 2.1614x; 1.2695x over previous
//
#include <hip/hip_runtime.h>
#include <cstddef>
#include <math.h>

// ---------------- problem constants ----------------
#define B_   2
#define L_   2048
#define D_   512
#define E_   768
static const size_t LL   = (size_t)L_ * L_;
static const size_t SLOT = (size_t)B_ * LL;

#define QK_N  ((size_t)B_ * L_ * D_)       // 2097152
#define G1_N  ((size_t)512 * 512)          // 262144
#define G_N   ((size_t)6 * G1_N)           // 1572864
#define U_N   ((size_t)6 * L_ * D_)        // 6291456

typedef unsigned short u16;
typedef __attribute__((ext_vector_type(8))) short short8;   // 8 bf16
typedef __attribute__((ext_vector_type(4))) float f32x4;

// ---------------- bf16x3 exact split of fp32 ---------------------------------
__device__ __forceinline__ u16 f2bf(float f) {
    unsigned x = __float_as_uint(f);
    unsigned r = (x + 0x7fffu + ((x >> 16) & 1u)) >> 16;    // RNE
    return (u16)r;
}
__device__ __forceinline__ float bf2f(u16 h) { return __uint_as_float(((unsigned)h) << 16); }
__device__ __forceinline__ void split3(float f, u16& h0, u16& h1, u16& h2) {
    h0 = f2bf(f); float r = f - bf2f(h0);
    h1 = f2bf(r); r -= bf2f(h1);
    h2 = f2bf(r);                                            // exact: fp32 = h0+h1+h2
}

#define BKP 40   // LDS row pitch in u16 (pad: frag reads ~2-way banks)

// ============ plane-based stagers =============================================
__device__ __forceinline__ void pstage_MK(const u16* __restrict__ P, size_t pstride, int ld,
                                          int r0, int k0, int tid, u16 S[3][64][BKP]) {
    int m = tid >> 2, kq = (tid & 3) << 3;
#pragma unroll
    for (int s = 0; s < 3; ++s) {
        const u16* src = P + (size_t)s * pstride + (size_t)(r0 + m) * ld + k0 + kq;
        ushort4 v0 = *reinterpret_cast<const ushort4*>(src);
        ushort4 v1 = *reinterpret_cast<const ushort4*>(src + 4);
        *reinterpret_cast<ushort4*>(&S[s][m][kq]) = v0;
        *reinterpret_cast<ushort4*>(&S[s][m][kq + 4]) = v1;
    }
}
__device__ __forceinline__ void pstage_KM(const u16* __restrict__ P, size_t pstride, int ld,
                                          int r0, int k0, int tid, u16 S[3][64][BKP]) {
    int k = tid >> 3, mq = (tid & 7) << 3;
#pragma unroll
    for (int s = 0; s < 3; ++s) {
        const u16* src = P + (size_t)s * pstride + (size_t)(k0 + k) * ld + r0 + mq;
        ushort4 v0 = *reinterpret_cast<const ushort4*>(src);
        ushort4 v1 = *reinterpret_cast<const ushort4*>(src + 4);
        S[s][mq + 0][k] = v0.x; S[s][mq + 1][k] = v0.y; S[s][mq + 2][k] = v0.z; S[s][mq + 3][k] = v0.w;
        S[s][mq + 4][k] = v1.x; S[s][mq + 5][k] = v1.y; S[s][mq + 6][k] = v1.z; S[s][mq + 7][k] = v1.w;
    }
}

// ============ 6-tier bf16x3 MFMA core (64x64 tile, BK=32) =====================
// tiers: H=a0b0; M=a0b1+a1b0 (2^-8); L=a0b2+a1b1+a2b0 (2^-16). Dropped 2^-26.
// H promoted to fp64 EVERY step, unconditionally — round-5-proven structure.
// (Round-7 lesson: `if (s&1)` promotion bloats VGPR 76->120 and breaks
//  pipelining -> MfmaUtil 41->18%. Do not reintroduce.)
template<bool AKM, bool BKM>
__device__ __forceinline__ void gemm_core(const u16* __restrict__ Ap, size_t Aps, int lda,
                                          const u16* __restrict__ Bp, size_t Bps, int ldb,
                                          int K, int m0, int n0, int tid,
                                          double outv[2][2][4]) {
    __shared__ u16 SA[3][64][BKP], SB[3][64][BKP];
    f32x4 accH[2][2], accM[2][2], accL[2][2];
#pragma unroll
    for (int i = 0; i < 2; ++i)
#pragma unroll
        for (int j = 0; j < 2; ++j) {
            accH[i][j] = (f32x4){0.f, 0.f, 0.f, 0.f};
            accM[i][j] = (f32x4){0.f, 0.f, 0.f, 0.f};
            accL[i][j] = (f32x4){0.f, 0.f, 0.f, 0.f};
        }
    double accD[2][2][4] = {};
    int lane = tid & 63, w = tid >> 6;
    int wm = (w & 1) << 5, wn = (w >> 1) << 5;
    int fr = lane & 15, ko = (lane >> 4) << 3;

    int nstep = K >> 5;
    for (int s = 0; s < nstep; ++s) {
        int k0 = s << 5;
        if (AKM) pstage_KM(Ap, Aps, lda, m0, k0, tid, SA); else pstage_MK(Ap, Aps, lda, m0, k0, tid, SA);
        if (BKM) pstage_KM(Bp, Bps, ldb, n0, k0, tid, SB); else pstage_MK(Bp, Bps, ldb, n0, k0, tid, SB);
        __syncthreads();
        short8 a[2][3], b[2][3];
#pragma unroll
        for (int f = 0; f < 2; ++f)
#pragma unroll
            for (int sp = 0; sp < 3; ++sp) {
                a[f][sp] = *reinterpret_cast<const short8*>(&SA[sp][wm + f * 16 + fr][ko]);
                b[f][sp] = *reinterpret_cast<const short8*>(&SB[sp][wn + f * 16 + fr][ko]);
            }
#pragma unroll
        for (int fi = 0; fi < 2; ++fi)
#pragma unroll
            for (int fj = 0; fj < 2; ++fj) {
                accH[fi][fj] = __builtin_amdgcn_mfma_f32_16x16x32_bf16(a[fi][0], b[fj][0], accH[fi][fj], 0, 0, 0);
                accM[fi][fj] = __builtin_amdgcn_mfma_f32_16x16x32_bf16(a[fi][0], b[fj][1], accM[fi][fj], 0, 0, 0);
                accM[fi][fj] = __builtin_amdgcn_mfma_f32_16x16x32_bf16(a[fi][1], b[fj][0], accM[fi][fj], 0, 0, 0);
                accL[fi][fj] = __builtin_amdgcn_mfma_f32_16x16x32_bf16(a[fi][0], b[fj][2], accL[fi][fj], 0, 0, 0);
                accL[fi][fj] = __builtin_amdgcn_mfma_f32_16x16x32_bf16(a[fi][1], b[fj][1], accL[fi][fj], 0, 0, 0);
                accL[fi][fj] = __builtin_amdgcn_mfma_f32_16x16x32_bf16(a[fi][2], b[fj][0], accL[fi][fj], 0, 0, 0);
            }
        __syncthreads();
#pragma unroll
        for (int fi = 0; fi < 2; ++fi)
#pragma unroll
            for (int fj = 0; fj < 2; ++fj) {
#pragma unroll
                for (int r = 0; r < 4; ++r) accD[fi][fj][r] += (double)accH[fi][fj][r];
                accH[fi][fj] = (f32x4){0.f, 0.f, 0.f, 0.f};
            }
    }
#pragma unroll
    for (int fi = 0; fi < 2; ++fi)
#pragma unroll
        for (int fj = 0; fj < 2; ++fj)
#pragma unroll
            for (int r = 0; r < 4; ++r)
                outv[fi][fj][r] = accD[fi][fj][r] + (double)accM[fi][fj][r] + (double)accL[fi][fj][r];
}

// ============ k_proj: fp32 sources, split3 staging, 6-tier ====================
__device__ __forceinline__ void stage_MKf(const float* __restrict__ P, int ld,
                                          int r0, int k0, int tid, u16 S[3][64][BKP]) {
#pragma unroll
    for (int i = 0; i < 2; ++i) {
        int f = tid + i * 256;
        int m = f >> 3, kq = (f & 7) << 2;
        float4 v = *reinterpret_cast<const float4*>(P + (size_t)(r0 + m) * ld + k0 + kq);
        float vv[4] = {v.x, v.y, v.z, v.w};
        u16 h[3][4];
#pragma unroll
        for (int c = 0; c < 4; ++c) split3(vv[c], h[0][c], h[1][c], h[2][c]);
#pragma unroll
        for (int s = 0; s < 3; ++s)
            *reinterpret_cast<ushort4*>(&S[s][m][kq]) = make_ushort4(h[s][0], h[s][1], h[s][2], h[s][3]);
    }
}

__global__ __launch_bounds__(256) void k_proj(const float* __restrict__ x,
                                              const float* __restrict__ Wq,
                                              const float* __restrict__ Wk,
                                              float* __restrict__ qraw,
                                              float* __restrict__ kraw) {
    __shared__ u16 SA[3][64][BKP], SB[3][64][BKP];
    const float* W = blockIdx.z ? Wk : Wq;
    float* out = blockIdx.z ? kraw : qraw;
    int tid = threadIdx.x;
    int m0 = blockIdx.y * 64, n0 = blockIdx.x * 64;
    f32x4 accH[2][2], accM[2][2], accL[2][2];
#pragma unroll
    for (int i = 0; i < 2; ++i)
#pragma unroll
        for (int j = 0; j < 2; ++j) {
            accH[i][j] = (f32x4){0.f, 0.f, 0.f, 0.f};
            accM[i][j] = (f32x4){0.f, 0.f, 0.f, 0.f};
            accL[i][j] = (f32x4){0.f, 0.f, 0.f, 0.f};
        }
    double accD[2][2][4] = {};
    int lane = tid & 63, w = tid >> 6;
    int wm = (w & 1) << 5, wn = (w >> 1) << 5;
    int fr = lane & 15, ko = (lane >> 4) << 3;
    for (int s = 0; s < (E_ >> 5); ++s) {
        int k0 = s << 5;
        stage_MKf(x, E_, m0, k0, tid, SA);
        stage_MKf(W, E_, n0, k0, tid, SB);
        __syncthreads();
        short8 a[2][3], b[2][3];
#pragma unroll
        for (int f = 0; f < 2; ++f)
#pragma unroll
            for (int sp = 0; sp < 3; ++sp) {
                a[f][sp] = *reinterpret_cast<const short8*>(&SA[sp][wm + f * 16 + fr][ko]);
                b[f][sp] = *reinterpret_cast<const short8*>(&SB[sp][wn + f * 16 + fr][ko]);
            }
#pragma unroll
        for (int fi = 0; fi < 2; ++fi)
#pragma unroll
            for (int fj = 0; fj < 2; ++fj) {
                accH[fi][fj] = __builtin_amdgcn_mfma_f32_16x16x32_bf16(a[fi][0], b[fj][0], accH[fi][fj], 0, 0, 0);
                accM[fi][fj] = __builtin_amdgcn_mfma_f32_16x16x32_bf16(a[fi][0], b[fj][1], accM[fi][fj], 0, 0, 0);
                accM[fi][fj] = __builtin_amdgcn_mfma_f32_16x16x32_bf16(a[fi][1], b[fj][0], accM[fi][fj], 0, 0, 0);
                accL[fi][fj] = __builtin_amdgcn_mfma_f32_16x16x32_bf16(a[fi][0], b[fj][2], accL[fi][fj], 0, 0, 0);
                accL[fi][fj] = __builtin_amdgcn_mfma_f32_16x16x32_bf16(a[fi][1], b[fj][1], accL[fi][fj], 0, 0, 0);
                accL[fi][fj] = __builtin_amdgcn_mfma_f32_16x16x32_bf16(a[fi][2], b[fj][0], accL[fi][fj], 0, 0, 0);
            }
        __syncthreads();
#pragma unroll
        for (int fi = 0; fi < 2; ++fi)
#pragma unroll
            for (int fj = 0; fj < 2; ++fj) {
#pragma unroll
                for (int r = 0; r < 4; ++r) accD[fi][fj][r] += (double)accH[fi][fj][r];
                accH[fi][fj] = (f32x4){0.f, 0.f, 0.f, 0.f};
            }
    }
    int col = lane & 15, rbase = (lane >> 4) << 2;
#pragma unroll
    for (int fi = 0; fi < 2; ++fi)
#pragma unroll
        for (int fj = 0; fj < 2; ++fj)
#pragma unroll
            for (int r = 0; r < 4; ++r) {
                double v = accD[fi][fj][r] + (double)accM[fi][fj][r] + (double)accL[fi][fj][r];
                int mm = m0 + wm + fi * 16 + rbase + r;
                int nn = n0 + wn + fj * 16 + col;
                out[(size_t)mm * D_ + nn] = (float)v;
            }
}

// ============ RoPE table (fp64, once per launch) ==============================
__global__ __launch_bounds__(256) void k_trig(double* __restrict__ tg) {
    int l = blockIdx.x, j = threadIdx.x;
    double e = (double)j * (1.0 / 256.0);
    double inv = pow(10000.0, -e);
    double ang = (double)l * inv;
    tg[(size_t)l * 512 + j] = cos(ang);
    tg[(size_t)l * 512 + 256 + j] = sin(ang);
}

// ============ LayerNorm + RoPE (fp64) -> bf16x3 planes ========================
__global__ __launch_bounds__(128) void k_lnrope(const float* __restrict__ qraw,
                                                const float* __restrict__ kraw,
                                                const double* __restrict__ tg,
                                                const float* __restrict__ qg, const float* __restrict__ qb,
                                                const float* __restrict__ kg, const float* __restrict__ kb,
                                                u16* __restrict__ qP, u16* __restrict__ kP) {
    int row = blockIdx.x;           // b*2048 + l
    int l = row & (L_ - 1);
    int tid = threadIdx.x;
    __shared__ double nrow[D_];
    __shared__ double red[4];
    __shared__ double cs_[256], sn_[256];
    for (int j = tid; j < 256; j += 128) {
        cs_[j] = tg[(size_t)l * 512 + j];
        sn_[j] = tg[(size_t)l * 512 + 256 + j];
    }
    __syncthreads();
    for (int pass = 0; pass < 2; ++pass) {
        const float* rp = (pass ? kraw : qraw) + (size_t)row * D_;
        const float* g  = pass ? kg : qg;
        const float* bt = pass ? kb : qb;
        u16* P = pass ? kP : qP;
        float4 v = reinterpret_cast<const float4*>(rp)[tid];
        double vv[4] = {(double)v.x, (double)v.y, (double)v.z, (double)v.w};
        double s = vv[0] + vv[1] + vv[2] + vv[3];
        double s2 = vv[0]*vv[0] + vv[1]*vv[1] + vv[2]*vv[2] + vv[3]*vv[3];
        for (int off = 32; off; off >>= 1) { s += __shfl_xor(s, off); s2 += __shfl_xor(s2, off); }
        int wv = tid >> 6;
        if ((tid & 63) == 0) { red[wv * 2] = s; red[wv * 2 + 1] = s2; }
        __syncthreads();
        double mu  = (red[0] + red[2]) * (1.0 / D_);
        double var = (red[1] + red[3]) * (1.0 / D_) - mu * mu;
        double rs = rsqrt(var + 1e-5);
        int d0 = tid * 4;
        double o[4];
#pragma unroll
        for (int c = 0; c < 4; ++c) {
            int d = d0 + c;
            o[c] = (vv[c] - mu) * rs * (double)g[d] + (double)bt[d];
        }
        __syncthreads();
#pragma unroll
        for (int c = 0; c < 4; ++c) nrow[d0 + c] = o[c];
        __syncthreads();
        u16 h[3][4];
#pragma unroll
        for (int c = 0; c < 4; ++c) {
            int d = d0 + c;
            double rot = (d < 256) ? -nrow[d + 256] : nrow[d - 256];
            float ov = (float)(nrow[d] * cs_[d & 255] + rot * sn_[d & 255]);
            split3(ov, h[0][c], h[1][c], h[2][c]);
        }
        size_t off = (size_t)row * D_ + d0;
#pragma unroll
        for (int sp = 0; sp < 3; ++sp)
            *reinterpret_cast<ushort4*>(P + sp * QK_N + off) = make_ushort4(h[sp][0], h[sp][1], h[sp][2], h[sp][3]);
        __syncthreads();
    }
}

// ============ Gram split-K=2: planes -> fp32 partials =========================
// blockIdx.z = z*2 + half; z = b*3+m
__global__ __launch_bounds__(256) void k_gram(const u16* __restrict__ qP,
                                              const u16* __restrict__ kP,
                                              float* __restrict__ Gpart) {
    int zz = blockIdx.z, half = zz & 1, z = zz >> 1;
    int b = z / 3, m = z % 3;
    const u16* A  = ((m == 2) ? qP : kP) + (size_t)b * L_ * D_ + (size_t)half * (L_ / 2) * D_;
    const u16* Bp = ((m == 0) ? kP : qP) + (size_t)b * L_ * D_ + (size_t)half * (L_ / 2) * D_;
    int m0 = blockIdx.y * 64, n0 = blockIdx.x * 64;
    double ov[2][2][4];
    gemm_core<true, true>(A, QK_N, D_, Bp, QK_N, D_, L_ / 2, m0, n0, threadIdx.x, ov);
    float* Gg = Gpart + (size_t)half * G_N + (size_t)z * G1_N;
    int lane = threadIdx.x & 63, w = threadIdx.x >> 6;
    int wm = (w & 1) << 5, wn = (w >> 1) << 5;
    int col = lane & 15, rbase = (lane >> 4) << 2;
#pragma unroll
    for (int fi = 0; fi < 2; ++fi)
#pragma unroll
        for (int fj = 0; fj < 2; ++fj)
#pragma unroll
            for (int r = 0; r < 4; ++r) {
                int mm = m0 + wm + fi * 16 + rbase + r;
                int nn = n0 + wn + fj * 16 + col;
                Gg[(size_t)mm * 512 + nn] = (float)ov[fi][fj][r];
            }
}

// ============ sum partials + split into G planes ==============================
__global__ __launch_bounds__(256) void k_gsplit(const float* __restrict__ Gpart,
                                                u16* __restrict__ GP) {
    size_t i = (size_t)blockIdx.x * 256 + threadIdx.x;   // over G_N
    float g = Gpart[i] + Gpart[G_N + i];
    u16 h0, h1, h2; split3(g, h0, h1, h2);
    GP[i] = h0; GP[G_N + i] = h1; GP[2 * G_N + i] = h2;
}

// ============ U = {q,q,k} @ G : planes -> U planes ============================
__global__ __launch_bounds__(256) void k_u(const u16* __restrict__ qP,
                                           const u16* __restrict__ kP,
                                           const u16* __restrict__ GP,
                                           u16* __restrict__ UP) {
    int z = blockIdx.z, b = z / 3, m = z % 3;
    const u16* A  = ((m == 2) ? kP : qP) + (size_t)b * L_ * D_;
    const u16* Bp = GP + (size_t)z * G1_N;
    int m0 = blockIdx.y * 64, n0 = blockIdx.x * 64;
    double ov[2][2][4];
    gemm_core<false, true>(A, QK_N, D_, Bp, G_N, 512, D_, m0, n0, threadIdx.x, ov);
    int lane = threadIdx.x & 63, w = threadIdx.x >> 6;
    int wm = (w & 1) << 5, wn = (w >> 1) << 5;
    int col = lane & 15, rbase = (lane >> 4) << 2;
#pragma unroll
    for (int fi = 0; fi < 2; ++fi)
#pragma unroll
        for (int fj = 0; fj < 2; ++fj)
#pragma unroll
            for (int r = 0; r < 4; ++r) {
                float uf = (float)ov[fi][fj][r];
                int mm = m0 + wm + fi * 16 + rbase + r;
                int nn = n0 + wn + fj * 16 + col;
                size_t off = (size_t)z * ((size_t)L_ * D_) + (size_t)mm * D_ + nn;
                u16 h0, h1, h2; split3(uf, h0, h1, h2);
                UP[off] = h0; UP[U_N + off] = h1; UP[2 * U_N + off] = h2;
            }
}

// ============ scores = U @ {q,k,k}^T : planes -> out slots 1..3 ===============
__global__ __launch_bounds__(256) void k_scores(const u16* __restrict__ qP,
                                                const u16* __restrict__ kP,
                                                const u16* __restrict__ UP,
                                                float* __restrict__ out) {
    int z = blockIdx.z, b = z / 3, m = z % 3;
    const u16* A  = UP + (size_t)z * ((size_t)L_ * D_);
    const u16* Bp = ((m == 0) ? qP : kP) + (size_t)b * L_ * D_;
    int m0 = blockIdx.y * 64, n0 = blockIdx.x * 64;
    double ov[2][2][4];
    gemm_core<false, false>(A, U_N, D_, Bp, QK_N, D_, D_, m0, n0, threadIdx.x, ov);
    float* Co = out + (size_t)(1 + m) * SLOT + (size_t)b * LL;
    int lane = threadIdx.x & 63, w = threadIdx.x >> 6;
    int wm = (w & 1) << 5, wn = (w >> 1) << 5;
    int col = lane & 15, rbase = (lane >> 4) << 2;
#pragma unroll
    for (int fi = 0; fi < 2; ++fi)
#pragma unroll
        for (int fj = 0; fj < 2; ++fj)
#pragma unroll
            for (int r = 0; r < 4; ++r) {
                int mm = m0 + wm + fi * 16 + rbase + r;
                int nn = n0 + wn + fj * 16 + col;
                Co[(size_t)mm * L_ + nn] = (float)ov[fi][fj][r];
            }
}

// ============ entmax-1.5: fp32 (subtract-max-first), 12 bisect + 4 Newton =====
// Error budget: support-element z error ~1e-7 (fp32 subtract near 0); fp32 sum
// noise ~1e-5 -> tau err ~1e-5 -> p err ~2e-5, vs threshold 2e-2.
__global__ __launch_bounds__(256) void k_entmax(float* __restrict__ base, int nrows,
                                                const float* __restrict__ wC,
                                                const float* __restrict__ wF,
                                                const float* __restrict__ wS,
                                                int clip) {
    int tid = threadIdx.x;
    int lane = tid & 63;
    int r = blockIdx.x * 4 + (tid >> 6);
    if (r >= nrows) return;
    float hw = 0.5f;
    if (wC) {
        int m = r >> 12;                 // 4096 rows per matrix
        const float* wp = (m == 0) ? wC : (m == 1) ? wF : wS;
        hw = (float)(1.0 / (1.0 + exp(-(double)wp[0])));   // 0.5 * w
    }
    float* row = base + (size_t)r * L_;
    float v[32];
    float mx = -3.4e38f;
#pragma unroll
    for (int j = 0; j < 32; ++j) {
        v[j] = row[lane + (j << 6)];
        mx = fmaxf(mx, v[j]);
    }
    for (int off = 32; off; off >>= 1) mx = fmaxf(mx, __shfl_xor(mx, off));
    float z[32];
#pragma unroll
    for (int j = 0; j < 32; ++j) z[j] = hw * (v[j] - mx);   // exact-max, small-err subtract
    float lo = -1.0f, hi = 0.0f;
    for (int it = 0; it < 12; ++it) {
        float tau = 0.5f * (lo + hi);
        float ssum = 0.0f;
#pragma unroll
        for (int j = 0; j < 32; ++j) {
            float t = fmaxf(z[j] - tau, 0.0f);
            ssum = fmaf(t, t, ssum);
        }
        for (int off = 32; off; off >>= 1) ssum += __shfl_xor(ssum, off);
        if (ssum >= 1.0f) lo = tau; else hi = tau;
    }
    float tau = lo;   // f(lo) >= 1; Newton on convex f approaches root from left
    for (int it = 0; it < 4; ++it) {
        float s1 = 0.0f, s2 = 0.0f;
#pragma unroll
        for (int j = 0; j < 32; ++j) {
            float t = fmaxf(z[j] - tau, 0.0f);
            s1 += t;
            s2 = fmaf(t, t, s2);
        }
        for (int off = 32; off; off >>= 1) { s1 += __shfl_xor(s1, off); s2 += __shfl_xor(s2, off); }
        float denom = 2.0f * s1;
        if (denom > 1e-30f) tau += fmaxf((s2 - 1.0f) / denom, 0.0f);
    }
#pragma unroll
    for (int j = 0; j < 32; ++j) {
        float t = fmaxf(z[j] - tau, 0.0f);
        float p = t * t;
        if (clip) p = fminf(p, 1.0f - 1e-6f);
        row[lane + (j << 6)] = p;
    }
}

// ============ column sums: partials (deterministic, parallel) =================
__global__ __launch_bounds__(256) void k_colsum(const float* __restrict__ out,
                                                double* __restrict__ part) {
    int bz = blockIdx.z, which = bz >> 1, b = bz & 1;
    const float* mat = out + (size_t)(which ? 3 : 1) * SLOT + (size_t)b * LL;
    int j = blockIdx.x * 256 + threadIdx.x;
    int r0 = blockIdx.y * 128;
    double s = 0.0;
#pragma unroll 8
    for (int r = 0; r < 128; ++r) s += (double)mat[(size_t)(r0 + r) * L_ + j];
    part[((size_t)bz * 16 + blockIdx.y) * L_ + j] = s;
}

__global__ __launch_bounds__(256) void k_colred(const double* __restrict__ part,
                                                double* __restrict__ csC,
                                                double* __restrict__ csS) {
    int g = blockIdx.x * 256 + threadIdx.x;   // 0..8191 = bz*2048 + j
    int bz = g >> 11, j = g & (L_ - 1);
    int which = bz >> 1, b = bz & 1;
    double s = 0.0;
#pragma unroll
    for (int c = 0; c < 16; ++c) s += part[((size_t)bz * 16 + c) * L_ + j];
    (which ? csS : csC)[b * L_ + j] = s;
}

// ============ finalize p's, build H (fp64, single log) ========================
__global__ __launch_bounds__(256) void k_finalize(float* __restrict__ out,
                                                  const double* __restrict__ csC,
                                                  const double* __restrict__ csS) {
    int row = blockIdx.x;               // b*2048 + i
    int i = row & (L_ - 1), b = row >> 11;
    size_t ro = (size_t)row * L_;
    float* H  = out + ro;
    float* pC = out + SLOT + ro;
    float* pF = out + 2 * SLOT + ro;
    float* pS = out + 3 * SLOT + ro;
    const double* cc = csC + b * L_;
    const double* cs = csS + b * L_;
    const double A1 = 1.0 - 2e-6;
    for (int j = threadIdx.x; j < L_; j += 256) {
        double c = (double)pC[j] * rsqrt(cc[j] + 1e-6);
        double f = (double)pF[j];
        double s = (double)pS[j] * rsqrt(cs[j] + 1e-6);
        c = fmax(A1 * c + 1e-6, 1e-6);
        f = fmax(A1 * f + 1e-6, 1e-6);
        s = fmax(A1 * s + 1e-6, 1e-6);
        pC[j] = (float)c; pF[j] = (float)f; pS[j] = (float)s;
        // log(c)+log(f)+log(s) == log(c*f*s); product in [1e-18,1] — fp64 safe
        H[j] = (j == i) ? -1e9f : (float)(log(c * f * s) * (1.0 / 3.0));
    }
}

// ============ launch ==========================================================
extern "C" void kernel_launch(void* const* d_in, const int* in_sizes, int n_in,
                              void* d_out, int out_size, void* d_ws, size_t ws_size,
                              hipStream_t stream) {
    const float* x  = (const float*)d_in[0];
    const float* Wq = (const float*)d_in[1];
    const float* Wk = (const float*)d_in[2];
    const float* qg = (const float*)d_in[3];
    const float* qb = (const float*)d_in[4];
    const float* kg = (const float*)d_in[5];
    const float* kb = (const float*)d_in[6];
    const float* wC = (const float*)d_in[7];
    const float* wF = (const float*)d_in[8];
    const float* wS = (const float*)d_in[9];
    float* out = (float*)d_out;

    // workspace (80.74 MB total — round-5/7 proven footprint).
    // Overlays (liveness-verified):
    //   qraw/kraw : UP bytes [0, 16.78 MB)     — dead after k_lnrope
    //   Gpart     : UP bytes [16.78, 29.36 MB) — dead after k_gsplit (pre-k_u)
    //   part/csC/csS : inside tg region        — tg dead after k_lnrope
    char* wsb = (char*)d_ws;
    u16*    UP   = (u16*)wsb;
    float*  qraw = (float*)wsb;
    float*  kraw = qraw + QK_N;
    float*  Gpart = (float*)(wsb + 2 * QK_N * sizeof(float));
    wsb += 3 * U_N * sizeof(u16);                               // 37.75 MB
    u16*    qP    = (u16*)wsb;   wsb += 3 * QK_N * sizeof(u16); // 12.6 MB
    u16*    kP    = (u16*)wsb;   wsb += 3 * QK_N * sizeof(u16); // 12.6 MB
    u16*    GP    = (u16*)wsb;   wsb += 3 * G_N * sizeof(u16);  // 9.4 MB
    double* tg    = (double*)wsb;                                // 8.4 MB region
    double* part  = tg;                                          // 1 MB   (alias)
    double* csC   = tg + (size_t)4 * 16 * L_;                    // 32 KB  (alias)
    double* csS   = csC + (size_t)B_ * L_;                       // 32 KB  (alias)

    k_trig    <<<dim3(L_),        256, 0, stream>>>(tg);
    k_proj    <<<dim3(8, 64, 2),  256, 0, stream>>>(x, Wq, Wk, qraw, kraw);
    k_lnrope  <<<dim3(B_ * L_),   128, 0, stream>>>(qraw, kraw, tg, qg, qb, kg, kb, qP, kP);
    k_gram    <<<dim3(8, 8, 12),  256, 0, stream>>>(qP, kP, Gpart);
    k_gsplit  <<<dim3(G_N / 256), 256, 0, stream>>>(Gpart, GP);
    k_u       <<<dim3(8, 32, 6),  256, 0, stream>>>(qP, kP, GP, UP);
    k_scores  <<<dim3(32, 32, 6), 256, 0, stream>>>(qP, kP, UP, out);
    k_entmax  <<<dim3(3072),      256, 0, stream>>>(out + SLOT, 3 * B_ * L_, wC, wF, wS, 1);
    k_colsum  <<<dim3(8, 16, 4),  256, 0, stream>>>(out, part);
    k_colred  <<<dim3(32),        256, 0, stream>>>(part, csC, csS);
    k_finalize<<<dim3(B_ * L_),   256, 0, stream>>>(out, csC, csS);
    k_entmax  <<<dim3(1024),      256, 0, stream>>>(out, B_ * L_, nullptr, nullptr, nullptr, 0);
}